// Round 7
// baseline (2082.765 us; speedup 1.0000x reference)
//
#include <hip/hip_runtime.h>
#include <math.h>

// AutoregressiveTransformer on MI355X (gfx950).
// Round 9: K-loop is LDS-read-BW bound (32KB LDS reads vs 78cyc MFMA per
// K-step -> ~27% MfmaUtil ceiling; matches r6/r7/r8 measurements 20-24%).
// (1) Revert to round-7 3-panel/2-barrier loop (best measured, 55.7us q|k).
// (2) q|k uses a 128x256 tile (FI=4,FJ=8): FLOP per LDS byte x1.33
//     (FI*FJ/(FI+FJ): 2.0 -> 2.67), LDS-BW ceiling ~40% util.
// (3) Keep round-8 vectorized softmax.

typedef unsigned short bfu;                                  // raw bf16 bits
typedef short  s16x8 __attribute__((ext_vector_type(8)));    // 8 bf16 = 4 VGPR
typedef float  f32x4 __attribute__((ext_vector_type(4)));    // MFMA C/D frag
typedef unsigned short u16x4 __attribute__((ext_vector_type(4)));

__device__ __forceinline__ bfu f2b(float f) {                // fp32 -> bf16 (RNE)
  unsigned int u = __float_as_uint(f);
  unsigned int r = (u + 0x7fffu + ((u >> 16) & 1u)) >> 16;
  return (bfu)r;
}
__device__ __forceinline__ float b2f(bfu h) {
  return __uint_as_float(((unsigned int)h) << 16);
}

// async global->LDS, 16 B per lane; LDS dest = wave-uniform base + lane*16
__device__ __forceinline__ void async16(const bfu* g, bfu* l) {
  __builtin_amdgcn_global_load_lds(
      (const __attribute__((address_space(1))) void*)g,
      (__attribute__((address_space(3))) void*)l, 16, 0, 0);
}

// counted vmcnt wait (literal immediates only)
template<int N> __device__ __forceinline__ void waitvm() {
  static_assert(N == 0 || N == 3 || N == 4 || N == 6 || N == 8 || N == 12,
                "vmcnt imm");
  if constexpr      (N == 0)  asm volatile("s_waitcnt vmcnt(0)"  ::: "memory");
  else if constexpr (N == 3)  asm volatile("s_waitcnt vmcnt(3)"  ::: "memory");
  else if constexpr (N == 4)  asm volatile("s_waitcnt vmcnt(4)"  ::: "memory");
  else if constexpr (N == 6)  asm volatile("s_waitcnt vmcnt(6)"  ::: "memory");
  else if constexpr (N == 8)  asm volatile("s_waitcnt vmcnt(8)"  ::: "memory");
  else                        asm volatile("s_waitcnt vmcnt(12)" ::: "memory");
}

// ---------------------------------------------------------------------------
// GEMM: C[m,n] = sum_k A[m,k] * Bt[n,k]  (both K-contiguous), bf16 in, fp32 acc.
// Tile TM x TN = (WY*FI*16) x (WX*FJ*16), WY*WX waves.
// K-loop: BK=32 panels in a 3-buffer rotation, depth-2 prefetch (round-7
// structure, best measured). Per iter:
//   stage(panel t+2) ; vmcnt(2*LP) ; s_barrier ; ds_read+MFMA ; s_barrier
// Steady-state vmcnt waits only on loads issued 2 iterations earlier; the
// second barrier protects panel reuse. R4-proven XOR column-group swizzle
// (SQ_LDS_BANK_CONFLICT=0). XCD-cluster block swizzle (cx x-tiles/cluster).
// Two-level z (zo=z/zInner, zi=z%zInner) for batch/head/split-K. CAUSAL:
// scale+mask epilogue + early-exit above diagonal. TRIK: K clamped to tM+TM.
// BIAS: 0 none, 1 col, 2 row. Requires K % 64 == 0 (all call sites satisfy).
// ---------------------------------------------------------------------------
template<int TM, int TN, int WY, int WX, int FI, int FJ,
         bool OUT_BF16, bool RELU, bool CAUSAL, int BIAS, bool TRIK>
__global__ __launch_bounds__(WY * WX * 64)
void gemm_bt(const bfu* __restrict__ A, long lda, long sAo, long sAi,
             const bfu* __restrict__ B, long ldb, long sBo, long sBi,
             void* __restrict__ Cv, long ldc, long sCo, long sCi,
             const float* __restrict__ bias,
             int K, int zInner, float scale, int cx)
{
  static_assert(TM == WY * FI * 16 && TN == WX * FJ * 16, "tile mismatch");
  constexpr int NW = WY * WX;
  constexpr int AI = TM / (16 * NW);              // A staging instrs/wave/panel
  constexpr int BI = TN / (16 * NW);              // B staging instrs/wave/panel
  constexpr int LP = AI + BI;                     // loads/wave/panel
  constexpr int APAN = TM * 32;                   // panel stride (elements)
  constexpr int BPAN = TN * 32;

  __shared__ __align__(16) bfu As[3 * APAN];
  __shared__ __align__(16) bfu Bs[3 * BPAN];

  // ---- XCD-cluster tile decode (total%8==0, cx|NX, cx|perX) ----
  const int NX = gridDim.x, NY = gridDim.y;
  const int flat  = blockIdx.x + NX * (blockIdx.y + NY * blockIdx.z);
  const int total = NX * NY * gridDim.z;
  const int xcd = flat & 7, idx = flat >> 3;
  const int perX = total >> 3;
  const int clX  = NX / cx;
  const int ry   = perX / cx;
  const int tx   = (xcd % clX) * cx + idx % cx;
  const int yz   = (xcd / clX) * ry + idx / cx;
  const int ty   = yz % NY, tz = yz / NY;

  const int tM = ty * TM;
  const int tN = tx * TN;
  if (CAUSAL && tN >= tM + TM) return;            // fully-masked tile

  const int zo = tz / zInner, zi = tz - zo * zInner;
  A += (long)zo * sAo + (long)zi * sAi;
  B += (long)zo * sBo + (long)zi * sBi;
  const long cBase = (long)zo * sCo + (long)zi * sCi;

  const int t = threadIdx.x;
  const int wave = t >> 6, lane = t & 63;
  const int wr = wave / WX, wc = wave % WX;
  const int q = lane >> 4, l16 = lane & 15;

  // ---- staging addresses (lane -> row lane/4, col-group (lane&3)^swz(row)) ----
  const bfu* aG[AI]; bfu* aL[AI];
  const bfu* bG[BI]; bfu* bL[BI];
#pragma unroll
  for (int i2 = 0; i2 < AI; i2++) {
    const int rb = (i2 * NW + wave) * 16;
    const int r  = rb + (lane >> 2);
    const int g  = (lane & 3) ^ ((r >> 1) & 3);
    aG[i2] = A + (long)(tM + r) * lda + g * 8;
    aL[i2] = &As[rb * 32];
  }
#pragma unroll
  for (int i2 = 0; i2 < BI; i2++) {
    const int rb = (i2 * NW + wave) * 16;
    const int r  = rb + (lane >> 2);
    const int g  = (lane & 3) ^ ((r >> 1) & 3);
    bG[i2] = B + (long)(tN + r) * ldb + g * 8;
    bL[i2] = &Bs[rb * 32];
  }

  // ---- fragment LDS offsets (swizzled; k-invariant, per panel) ----
  int aOff[FI], bOff[FJ];
#pragma unroll
  for (int i = 0; i < FI; i++) {
    const int r = wr * FI * 16 + i * 16 + l16;
    aOff[i] = r * 32 + ((q ^ ((r >> 1) & 3)) * 8);
  }
#pragma unroll
  for (int j = 0; j < FJ; j++) {
    const int r = wc * FJ * 16 + j * 16 + l16;
    bOff[j] = r * 32 + ((q ^ ((r >> 1) & 3)) * 8);
  }

  const int Kend = TRIK ? ((tM + TM < K) ? tM + TM : K) : K;
  const int nt   = Kend >> 5;                     // BK=32 stages

  // stage panel pan with K-offset k (LP async16 per wave)
  auto stage = [&](int pan, int k) {
#pragma unroll
    for (int i2 = 0; i2 < AI; i2++) async16(aG[i2] + k, aL[i2] + pan * APAN);
#pragma unroll
    for (int i2 = 0; i2 < BI; i2++) async16(bG[i2] + k, bL[i2] + pan * BPAN);
  };

  f32x4 acc[FI][FJ] = {};

  // prologue: depth-2 prefetch
  stage(0, 0);
  if (nt > 1) stage(1, 32);

  int pc = 0, ps = 2;                             // current / stage-ahead panel
  for (int tt = 0; tt < nt; ++tt) {
    if (tt + 2 < nt) { stage(ps, (tt + 2) * 32); waitvm<2 * LP>(); }
    else if (tt + 1 < nt) waitvm<LP>();
    else waitvm<0>();
    __builtin_amdgcn_s_barrier();                 // panel pc ready (all waves)
    __builtin_amdgcn_sched_barrier(0);            // pin ds_reads below barrier

    s16x8 af[FI], bfr[FJ];
#pragma unroll
    for (int i = 0; i < FI; i++) af[i]  = *(const s16x8*)&As[pc * APAN + aOff[i]];
#pragma unroll
    for (int j = 0; j < FJ; j++) bfr[j] = *(const s16x8*)&Bs[pc * BPAN + bOff[j]];

    __builtin_amdgcn_s_setprio(1);
#pragma unroll
    for (int i = 0; i < FI; i++)
#pragma unroll
      for (int j = 0; j < FJ; j++)
        acc[i][j] = __builtin_amdgcn_mfma_f32_16x16x32_bf16(af[i], bfr[j], acc[i][j], 0, 0, 0);
    __builtin_amdgcn_s_setprio(0);

    __builtin_amdgcn_s_barrier();                 // all reads of pc done -> reusable
    pc = (pc == 2) ? 0 : pc + 1;
    ps = (ps == 2) ? 0 : ps + 1;
  }

  // Epilogue. C/D layout (m89/m91): col = lane&15, row = (lane>>4)*4 + reg.
  float* Cf = (float*)Cv;
  bfu*   Cb = (bfu*)Cv;
#pragma unroll
  for (int i = 0; i < FI; i++) {
    const int row0 = tM + wr * FI * 16 + i * 16 + q * 4;
#pragma unroll
    for (int j = 0; j < FJ; j++) {
      const int col = tN + wc * FJ * 16 + j * 16 + l16;
      float cbv = 0.0f;
      if (BIAS == 1) cbv = bias[col];
#pragma unroll
      for (int r = 0; r < 4; r++) {
        float v = acc[i][j][r];
        if (CAUSAL) { v *= scale; if (col > row0 + r) v = -1e30f; }
        if (BIAS == 1) v += cbv;
        if (BIAS == 2) v += bias[row0 + r];
        if (RELU) v = fmaxf(v, 0.0f);
        long idxc = cBase + (long)(row0 + r) * ldc + col;
        if (OUT_BF16) Cb[idxc] = f2b(v); else Cf[idxc] = v;
      }
    }
  }
}

// ---------------------------------------------------------------------------
// fp32 [R,C] -> bf16 [C,R] transpose+convert (used for W_out)
// ---------------------------------------------------------------------------
__global__ void transpose_cvt(const float* __restrict__ src, bfu* __restrict__ dst,
                              int R, int C)
{
  __shared__ bfu tile[64 * 65];
  const int t = threadIdx.x;
  const int tc = blockIdx.x * 64, tr = blockIdx.y * 64;
#pragma unroll
  for (int i = 0; i < 16; i++) {
    int idx = t + i * 256; int r = idx >> 6, c = idx & 63;
    tile[r * 65 + c] = f2b(src[(long)(tr + r) * C + tc + c]);
  }
  __syncthreads();
#pragma unroll
  for (int i = 0; i < 16; i++) {
    int idx = t + i * 256; int r = idx >> 6, c = idx & 63;
    dst[(long)(tc + r) * R + tr + c] = tile[c * 65 + r];
  }
}

// ---------------------------------------------------------------------------
// Fused per-layer weight prep (transposes + q|k bias pack). 2592 blocks.
// ---------------------------------------------------------------------------
__global__ void prep_layer(const float* __restrict__ Wq, const float* __restrict__ Wk,
                           const float* __restrict__ Wv, const float* __restrict__ Wo,
                           const float* __restrict__ W1, const float* __restrict__ W2,
                           const float* __restrict__ bq, const float* __restrict__ bk,
                           bfu* __restrict__ qkvwT, bfu* __restrict__ woT,
                           bfu* __restrict__ w1T, bfu* __restrict__ w2T,
                           float* __restrict__ qkb)
{
  const int bid = blockIdx.x;
  const int t = threadIdx.x;

  if (bid >= 2560) {                        // bias pack: 8192 elems, 32 blocks
    int j = (bid - 2560) * 256 + t;
    qkb[j] = (j < 4096) ? bq[j] : bk[j - 4096];
    return;
  }

  const float* src; bfu* dst; int R, C, ctiles, local;
  if (bid < 512)       { src = Wq; dst = qkvwT;              R = 512;  C = 4096; ctiles = 64; local = bid; }
  else if (bid < 1024) { src = Wk; dst = qkvwT + 4096L*512;  R = 512;  C = 4096; ctiles = 64; local = bid - 512; }
  else if (bid < 1536) { src = Wv; dst = qkvwT + 8192L*512;  R = 512;  C = 4096; ctiles = 64; local = bid - 1024; }
  else if (bid < 2048) { src = Wo; dst = woT;                R = 4096; C = 512;  ctiles = 8;  local = bid - 1536; }
  else if (bid < 2304) { src = W1; dst = w1T;                R = 512;  C = 2048; ctiles = 32; local = bid - 2048; }
  else                 { src = W2; dst = w2T;                R = 2048; C = 512;  ctiles = 8;  local = bid - 2304; }
  const int tc = (local % ctiles) * 64;
  const int tr = (local / ctiles) * 64;

  __shared__ bfu tile[64 * 65];
#pragma unroll
  for (int i = 0; i < 16; i++) {
    int idx = t + i * 256; int r = idx >> 6, c = idx & 63;
    tile[r * 65 + c] = f2b(src[(long)(tr + r) * C + tc + c]);
  }
  __syncthreads();
#pragma unroll
  for (int i = 0; i < 16; i++) {
    int idx = t + i * 256; int r = idx >> 6, c = idx & 63;
    dst[(long)(tc + r) * R + tr + c] = tile[c * 65 + r];
  }
}

// block (256 threads) stats over 512 values (2/thread pre-summed by caller)
__device__ __forceinline__ void blk_stats(float s, float ss, float* red,
                                          float& mean, float& var)
{
#pragma unroll
  for (int off = 32; off; off >>= 1) { s += __shfl_down(s, off); ss += __shfl_down(ss, off); }
  int w = threadIdx.x >> 6;
  if ((threadIdx.x & 63) == 0) { red[w] = s; red[4 + w] = ss; }
  __syncthreads();
  s  = red[0] + red[1] + red[2] + red[3];
  ss = red[4] + red[5] + red[6] + red[7];
  mean = s * (1.0f / 512.0f);
  var  = ss * (1.0f / 512.0f) - mean * mean;
}

__global__ void embed_ln(const int* __restrict__ ids, const float* __restrict__ tok,
                         const float* __restrict__ pos, const float* __restrict__ g,
                         const float* __restrict__ bta, float* __restrict__ h,
                         bfu* __restrict__ hb)
{
  __shared__ float red[8];
  const int row = blockIdx.x;          // b*S + s
  const int s = row & 1023;
  const int t = threadIdx.x;
  const long base = (long)row * 512;
  const int id = ids[row];
  float x0 = tok[(long)id * 512 + t]       + pos[(long)s * 512 + t];
  float x1 = tok[(long)id * 512 + t + 256] + pos[(long)s * 512 + t + 256];
  float mean, var;
  blk_stats(x0 + x1, x0 * x0 + x1 * x1, red, mean, var);
  float rstd = rsqrtf(var + 1e-5f);
  float y0 = (x0 - mean) * rstd * g[t]       + bta[t];
  float y1 = (x1 - mean) * rstd * g[t + 256] + bta[t + 256];
  h[base + t] = y0;        h[base + t + 256] = y1;
  hb[base + t] = f2b(y0);  hb[base + t + 256] = f2b(y1);
}

// x = sum_{s<n} p[i+s*ps] + bias[col] + h[i] -> LN -> h, hb
__global__ void add_ln_redN(const float* __restrict__ p, long ps, int n,
                            const float* __restrict__ bias,
                            float* __restrict__ h, bfu* __restrict__ hb,
                            const float* __restrict__ g, const float* __restrict__ bta)
{
  __shared__ float red[8];
  const long base = (long)blockIdx.x * 512;
  const int t = threadIdx.x;
  float x0 = bias[t]       + h[base + t];
  float x1 = bias[t + 256] + h[base + t + 256];
  for (int s = 0; s < n; s++) {
    x0 += p[base + (long)s * ps + t];
    x1 += p[base + (long)s * ps + t + 256];
  }
  float mean, var;
  blk_stats(x0 + x1, x0 * x0 + x1 * x1, red, mean, var);
  float rstd = rsqrtf(var + 1e-5f);
  float y0 = (x0 - mean) * rstd * g[t]       + bta[t];
  float y1 = (x1 - mean) * rstd * g[t + 256] + bta[t + 256];
  h[base + t] = y0;        h[base + t + 256] = y1;
  hb[base + t] = f2b(y0);  hb[base + t + 256] = f2b(y1);
}

// out[i] = sum_{s<n} p[i+s*ps] + bias[col]
__global__ void out_redN(const float* __restrict__ p, long ps, int n,
                         const float* __restrict__ bias, float* __restrict__ out)
{
  const long base = (long)blockIdx.x * 512;
  const int t = threadIdx.x;
  float x0 = bias[t], x1 = bias[t + 256];
  for (int s = 0; s < n; s++) {
    x0 += p[base + (long)s * ps + t];
    x1 += p[base + (long)s * ps + t + 256];
  }
  out[base + t] = x0;
  out[base + t + 256] = x1;
}

// Causal in-place softmax, row r = blockIdx.x & 1023 of a 1024-wide bf16 row.
// Vectorized: thread t owns 4 contiguous cols (u16x4 load/store).
// Reads cols <= r only (others masked); writes cols < roundup128(r+1).
__global__ void softmax_causal(bfu* __restrict__ P)
{
  __shared__ float red[8];
  const long base = (long)blockIdx.x * 1024;
  const int r = blockIdx.x & 1023;
  const int wlim = ((r >> 7) + 1) << 7;          // multiple of 128 (and of 4)
  const int t = threadIdx.x;
  const int c0 = t * 4;
  u16x4 pk = *(const u16x4*)&P[base + c0];
  float v[4];
  float mx = -3e30f;
#pragma unroll
  for (int i = 0; i < 4; i++) {
    const int col = c0 + i;
    v[i] = (col <= r) ? b2f(pk[i]) : -3e30f;
    mx = fmaxf(mx, v[i]);
  }
#pragma unroll
  for (int off = 32; off; off >>= 1) mx = fmaxf(mx, __shfl_xor(mx, off));
  int w = t >> 6;
  if ((t & 63) == 0) red[w] = mx;
  __syncthreads();
  mx = fmaxf(fmaxf(red[0], red[1]), fmaxf(red[2], red[3]));
  float e[4], sum = 0.0f;
#pragma unroll
  for (int i = 0; i < 4; i++) {
    const int col = c0 + i;
    e[i] = (col <= r) ? expf(v[i] - mx) : 0.0f;
    sum += e[i];
  }
#pragma unroll
  for (int off = 32; off; off >>= 1) sum += __shfl_xor(sum, off);
  __syncthreads();
  if ((t & 63) == 0) red[4 + w] = sum;
  __syncthreads();
  sum = red[4] + red[5] + red[6] + red[7];
  float inv = 1.0f / sum;
  if (c0 < wlim) {
    u16x4 o;
#pragma unroll
    for (int i = 0; i < 4; i++) o[i] = f2b(e[i] * inv);
    *(u16x4*)&P[base + c0] = o;
  }
}

// ---------------------------------------------------------------------------
extern "C" void kernel_launch(void* const* d_in, const int* in_sizes, int n_in,
                              void* d_out, int out_size, void* d_ws, size_t ws_size,
                              hipStream_t stream)
{
  const int*   x     = (const int*)  d_in[0];
  const float* tok   = (const float*)d_in[1];
  const float* pos   = (const float*)d_in[2];
  const float* lnig  = (const float*)d_in[3];
  const float* lnib  = (const float*)d_in[4];
  const float* Wq    = (const float*)d_in[5];
  const float* bq    = (const float*)d_in[6];
  const float* Wk    = (const float*)d_in[7];
  const float* bk    = (const float*)d_in[8];
  const float* Wv    = (const float*)d_in[9];
  const float* bv    = (const float*)d_in[10];
  const float* Wo    = (const float*)d_in[11];
  const float* bo    = (const float*)d_in[12];
  const float* ln1g  = (const float*)d_in[13];
  const float* ln1b  = (const float*)d_in[14];
  const float* W1    = (const float*)d_in[15];
  const float* b1    = (const float*)d_in[16];
  const float* W2    = (const float*)d_in[17];
  const float* b2    = (const float*)d_in[18];
  const float* ln2g  = (const float*)d_in[19];
  const float* ln2b  = (const float*)d_in[20];
  const float* Wout  = (const float*)d_in[21];
  const float* bout  = (const float*)d_in[22];

  // ---- workspace tiering (deterministic in ws_size) ----
  const size_t MB = 1024 * 1024;
  int gb; bool s4;                           // batches per attention group; split-K=4 path
  if      (ws_size >= 236 * MB) { gb = 4; s4 = true;  }
  else if (ws_size >= 169 * MB) { gb = 2; s4 = true;  }
  else if (ws_size >= 152 * MB) { gb = 1; s4 = true;  }
  else                          { gb = 1; s4 = false; }   // == round-4 layout (~110 MB)

  const size_t qkBytes = (size_t)gb * 1024 * 8192 * 2;
  const size_t scB0    = (size_t)gb * 8 * 1024 * 1024 * 2;
  const size_t scBytes = s4 ? (scB0 > 33554432 ? scB0 : 33554432) : 16777216;
  const size_t vtB0    = (size_t)gb * 8 * 512 * 1024 * 2;
  const size_t vtBytes = s4 ? (vtB0 > 33554432 ? vtB0 : 33554432) : 8388608;

  char* wsp = (char*)d_ws;
  auto alloc = [&](size_t bytes) { char* p = wsp; wsp += (bytes + 255) & ~(size_t)255; return p; };

  bfu*   qkvwT = (bfu*)  alloc(12288L * 512 * 2);
  bfu*   woT   = (bfu*)  alloc(512L * 4096 * 2);
  bfu*   w1T   = (bfu*)  alloc(2048L * 512 * 2);
  bfu*   w2T   = (bfu*)  alloc(512L * 2048 * 2);
  bfu*   woutT = (bfu*)  alloc(512L * 512 * 2);
  float* qkb   = (float*)alloc(8192L * 4);
  float* h     = (float*)alloc(4096L * 512 * 4);        // fp32 residual stream
  bfu*   hb    = (bfu*)  alloc(4096L * 512 * 2);        // bf16 copy (GEMM A operand)
  bfu*   attn  = (bfu*)  alloc(4096L * 4096 * 2);       // attention out, all tokens
  bfu*   qkS   = (bfu*)  alloc(qkBytes);                // q|k group; (!s4) FFN2/final partials
  bfu*   scS   = (bfu*)  alloc(scBytes);                // scores; Wo partials; FFN hidden
  bfu*   vTS   = (bfu*)  alloc(vtBytes);                // v^T group; (s4) FFN2/final partials

  float* pWo = (float*)scS;
  float* pF  = s4 ? (float*)vTS : (float*)qkS;
  const int nspl = s4 ? 4 : 2;

  embed_ln<<<4096, 256, 0, stream>>>(x, tok, pos, lnig, lnib, h, hb);
  transpose_cvt<<<dim3(8, 8), 256, 0, stream>>>(Wout, woutT, 512, 512);

  const float invsq = 0.044194173824159216f;  // 1/sqrt(512)
  const long  PSTR  = 4096L * 512;            // split-K partial stride (floats)

  for (int l = 0; l < 6; l++) {
    prep_layer<<<2592, 256, 0, stream>>>(
        Wq + (long)l*512*4096, Wk + (long)l*512*4096, Wv + (long)l*512*4096,
        Wo + (long)l*4096*512, W1 + (long)l*512*2048, W2 + (long)l*2048*512,
        bq + (long)l*4096, bk + (long)l*4096,
        qkvwT, woT, w1T, w2T, qkb);

    for (int g0 = 0; g0 < 4; g0 += gb) {
      const bfu* hbG = hb + (long)g0 * 1024 * 512;

      // q|k: [gb*1024,512] x [8192,512]^T -> qkS (+col bias), 128x256 tile
      gemm_bt<128,256,2,2,4,8,true,false,false,1,false>
          <<<dim3(32, gb*8, 1), 256, 0, stream>>>(
          hbG, 512, 0, 0, qkvwT, 512, 0, 0, qkS, 8192, 0, 0,
          qkb, 512, 1, 1.0f, 8);

      // vT[b][h][d][s] = Wv^T @ h_b^T (+row bias): z = batch
      gemm_bt<128,128,2,2,4,4,true,false,false,2,false>
          <<<dim3(8, 32, gb), 256, 0, stream>>>(
          qkvwT + 8192L*512, 512, 0, 0,
          hbG, 512, 0, 1024L*512,
          vTS, 1024, 0, 4096L*1024,
          bv + (long)l*4096, 512, gb, 1.0f, 8);

      // scores = (q k^T)/sqrt(dh), causal (upper tiles skipped): z = b*8+h
      gemm_bt<128,128,2,2,4,4,true,false,true,0,false>
          <<<dim3(8, 8, gb*8), 256, 0, stream>>>(
          qkS,        8192, 1024L*8192, 512,
          qkS + 4096, 8192, 1024L*8192, 512,
          scS, 1024, 8L*1024*1024, 1024L*1024,
          nullptr, 512, 8, invsq, 8);

      softmax_causal<<<gb*8192, 256, 0, stream>>>(scS);

      // attn = P @ v, triangular K: z = b*8+h
      gemm_bt<128,64,2,2,4,2,true,false,false,0,true>
          <<<dim3(8, 8, gb*8), 256, 0, stream>>>(
          scS, 1024, 8L*1024*1024, 1024L*1024,
          vTS, 1024, 8L*512*1024,  512L*1024,
          attn + (long)g0*1024*4096, 4096, 1024L*4096, 512,
          nullptr, 1024, 8, 1.0f, 8);
    }

    // Wo projection -> fp32 partials
    if (s4) {
      gemm_bt<128,128,2,2,4,4,false,false,false,0,false>
          <<<dim3(4, 32, 4), 256, 0, stream>>>(
          attn, 4096, 0, 1024, woT, 4096, 0, 1024,
          pWo, 512, 0, PSTR, nullptr, 1024, 4, 1.0f, 4);
    } else {
      gemm_bt<128,64,2,2,4,2,false,false,false,0,false>
          <<<dim3(8, 32, 2), 256, 0, stream>>>(
          attn, 4096, 0, 2048, woT, 4096, 0, 2048,
          pWo, 512, 0, PSTR, nullptr, 2048, 1, 1.0f, 8);
    }
    add_ln_redN<<<4096, 256, 0, stream>>>(pWo, PSTR, nspl, bo + (long)l*512,
                                          h, hb, ln1g + (long)l*512, ln1b + (long)l*512);

    // FFN1 (+ReLU) -> bf16 hidden in scS [4096,2048]
    gemm_bt<128,128,2,2,4,4,true,true,false,1,false>
        <<<dim3(16, 32, 1), 256, 0, stream>>>(
        hb, 512, 0, 0, w1T, 512, 0, 0, scS, 2048, 0, 0,
        b1 + (long)l*2048, 512, 1, 1.0f, 16);

    // FFN2 -> fp32 partials
    if (s4) {
      gemm_bt<128,128,2,2,4,4,false,false,false,0,false>
          <<<dim3(4, 32, 4), 256, 0, stream>>>(
          scS, 2048, 0, 512, w2T, 2048, 0, 512,
          pF, 512, 0, PSTR, nullptr, 512, 4, 1.0f, 4);
    } else {
      gemm_bt<128,64,2,2,4,2,false,false,false,0,false>
          <<<dim3(8, 32, 2), 256, 0, stream>>>(
          scS, 2048, 0, 1024, w2T, 2048, 0, 1024,
          pF, 512, 0, PSTR, nullptr, 1024, 1, 1.0f, 8);
    }
    add_ln_redN<<<4096, 256, 0, stream>>>(pF, PSTR, nspl, b2 + (long)l*512,
                                          h, hb, ln2g + (long)l*512, ln2b + (long)l*512);
  }

  // final projection (K=128 per split: multiple of 64 ✓)
  if (s4) {
    gemm_bt<128,128,2,2,4,4,false,false,false,0,false>
        <<<dim3(4, 32, 4), 256, 0, stream>>>(
        hb, 512, 0, 128, woutT, 512, 0, 128,
        pF, 512, 0, PSTR, nullptr, 128, 4, 1.0f, 4);
  } else {
    gemm_bt<128,64,2,2,4,2,false,false,false,0,false>
        <<<dim3(8, 32, 2), 256, 0, stream>>>(
        hb, 512, 0, 256, woutT, 512, 0, 256,
        pF, 512, 0, PSTR, nullptr, 256, 1, 1.0f, 8);
  }
  out_redN<<<4096, 256, 0, stream>>>(pF, PSTR, nspl, bout, (float*)d_out);
}

// Round 8
// 1940.852 us; speedup vs baseline: 1.0731x; 1.0731x over previous
//
#include <hip/hip_runtime.h>
#include <math.h>

// AutoregressiveTransformer on MI355X (gfx950).
// Round 10: occupancy is the governing variable (r6-r9 record: dur tracks
// OccupancyPercent; tile/barrier experiments at lower occupancy all lost).
// (1) gemm_bt = round-7 3-panel pipeline exactly (proven best, 55.7us q|k).
// (2) PV GEMM tile 128x64 -> 128x128 (cx=4): FLOP/LDS-byte 1.33 -> 2.0.
// (3) round-8 vectorized softmax (proven -34us).
// (4) transpose tiles padded 65->66 (bank stride 33, kills the 327K
//     conflicts rocprof showed on prep_layer's transposed reads).

typedef unsigned short bfu;                                  // raw bf16 bits
typedef short  s16x8 __attribute__((ext_vector_type(8)));    // 8 bf16 = 4 VGPR
typedef float  f32x4 __attribute__((ext_vector_type(4)));    // MFMA C/D frag
typedef unsigned short u16x4 __attribute__((ext_vector_type(4)));

__device__ __forceinline__ bfu f2b(float f) {                // fp32 -> bf16 (RNE)
  unsigned int u = __float_as_uint(f);
  unsigned int r = (u + 0x7fffu + ((u >> 16) & 1u)) >> 16;
  return (bfu)r;
}
__device__ __forceinline__ float b2f(bfu h) {
  return __uint_as_float(((unsigned int)h) << 16);
}

// async global->LDS, 16 B per lane; LDS dest = wave-uniform base + lane*16
__device__ __forceinline__ void async16(const bfu* g, bfu* l) {
  __builtin_amdgcn_global_load_lds(
      (const __attribute__((address_space(1))) void*)g,
      (__attribute__((address_space(3))) void*)l, 16, 0, 0);
}

// counted vmcnt wait (literal immediates only)
template<int N> __device__ __forceinline__ void waitvm() {
  static_assert(N == 0 || N == 3 || N == 4 || N == 6 || N == 8, "vmcnt imm");
  if constexpr      (N == 0) asm volatile("s_waitcnt vmcnt(0)" ::: "memory");
  else if constexpr (N == 3) asm volatile("s_waitcnt vmcnt(3)" ::: "memory");
  else if constexpr (N == 4) asm volatile("s_waitcnt vmcnt(4)" ::: "memory");
  else if constexpr (N == 6) asm volatile("s_waitcnt vmcnt(6)" ::: "memory");
  else                       asm volatile("s_waitcnt vmcnt(8)" ::: "memory");
}

// ---------------------------------------------------------------------------
// GEMM: C[m,n] = sum_k A[m,k] * Bt[n,k]  (both K-contiguous), bf16 in, fp32 acc.
// Tile TM x TN = (WY*FI*16) x (WX*FJ*16), WY*WX waves.
// K-loop: BK=32 panels in a 3-buffer rotation, depth-2 prefetch (round-7
// structure, best measured). Per iter:
//   stage(panel t+2) ; vmcnt(2*LP) ; s_barrier ; ds_read+MFMA ; s_barrier
// Steady-state vmcnt waits only on loads issued 2 iterations earlier; the
// second barrier protects panel reuse. R4-proven XOR column-group swizzle
// (SQ_LDS_BANK_CONFLICT=0). XCD-cluster block swizzle (cx x-tiles/cluster).
// Two-level z (zo=z/zInner, zi=z%zInner) for batch/head/split-K. CAUSAL:
// scale+mask epilogue + early-exit above diagonal. TRIK: K clamped to tM+TM.
// BIAS: 0 none, 1 col, 2 row. Requires K % 64 == 0 (all call sites satisfy).
// ---------------------------------------------------------------------------
template<int TM, int TN, int WY, int WX, int FI, int FJ,
         bool OUT_BF16, bool RELU, bool CAUSAL, int BIAS, bool TRIK>
__global__ __launch_bounds__(WY * WX * 64)
void gemm_bt(const bfu* __restrict__ A, long lda, long sAo, long sAi,
             const bfu* __restrict__ B, long ldb, long sBo, long sBi,
             void* __restrict__ Cv, long ldc, long sCo, long sCi,
             const float* __restrict__ bias,
             int K, int zInner, float scale, int cx)
{
  static_assert(TM == WY * FI * 16 && TN == WX * FJ * 16, "tile mismatch");
  constexpr int NW = WY * WX;
  constexpr int AI = TM / (16 * NW);              // A staging instrs/wave/panel
  constexpr int BI = TN / (16 * NW);              // B staging instrs/wave/panel
  constexpr int LP = AI + BI;                     // loads/wave/panel
  constexpr int APAN = TM * 32;                   // panel stride (elements)
  constexpr int BPAN = TN * 32;

  __shared__ __align__(16) bfu As[3 * APAN];
  __shared__ __align__(16) bfu Bs[3 * BPAN];

  // ---- XCD-cluster tile decode (total%8==0, cx|NX, cx|perX) ----
  const int NX = gridDim.x, NY = gridDim.y;
  const int flat  = blockIdx.x + NX * (blockIdx.y + NY * blockIdx.z);
  const int total = NX * NY * gridDim.z;
  const int xcd = flat & 7, idx = flat >> 3;
  const int perX = total >> 3;
  const int clX  = NX / cx;
  const int ry   = perX / cx;
  const int tx   = (xcd % clX) * cx + idx % cx;
  const int yz   = (xcd / clX) * ry + idx / cx;
  const int ty   = yz % NY, tz = yz / NY;

  const int tM = ty * TM;
  const int tN = tx * TN;
  if (CAUSAL && tN >= tM + TM) return;            // fully-masked tile

  const int zo = tz / zInner, zi = tz - zo * zInner;
  A += (long)zo * sAo + (long)zi * sAi;
  B += (long)zo * sBo + (long)zi * sBi;
  const long cBase = (long)zo * sCo + (long)zi * sCi;

  const int t = threadIdx.x;
  const int wave = t >> 6, lane = t & 63;
  const int wr = wave / WX, wc = wave % WX;
  const int q = lane >> 4, l16 = lane & 15;

  // ---- staging addresses (lane -> row lane/4, col-group (lane&3)^swz(row)) ----
  const bfu* aG[AI]; bfu* aL[AI];
  const bfu* bG[BI]; bfu* bL[BI];
#pragma unroll
  for (int i2 = 0; i2 < AI; i2++) {
    const int rb = (i2 * NW + wave) * 16;
    const int r  = rb + (lane >> 2);
    const int g  = (lane & 3) ^ ((r >> 1) & 3);
    aG[i2] = A + (long)(tM + r) * lda + g * 8;
    aL[i2] = &As[rb * 32];
  }
#pragma unroll
  for (int i2 = 0; i2 < BI; i2++) {
    const int rb = (i2 * NW + wave) * 16;
    const int r  = rb + (lane >> 2);
    const int g  = (lane & 3) ^ ((r >> 1) & 3);
    bG[i2] = B + (long)(tN + r) * ldb + g * 8;
    bL[i2] = &Bs[rb * 32];
  }

  // ---- fragment LDS offsets (swizzled; k-invariant, per panel) ----
  int aOff[FI], bOff[FJ];
#pragma unroll
  for (int i = 0; i < FI; i++) {
    const int r = wr * FI * 16 + i * 16 + l16;
    aOff[i] = r * 32 + ((q ^ ((r >> 1) & 3)) * 8);
  }
#pragma unroll
  for (int j = 0; j < FJ; j++) {
    const int r = wc * FJ * 16 + j * 16 + l16;
    bOff[j] = r * 32 + ((q ^ ((r >> 1) & 3)) * 8);
  }

  const int Kend = TRIK ? ((tM + TM < K) ? tM + TM : K) : K;
  const int nt   = Kend >> 5;                     // BK=32 stages

  // stage panel pan with K-offset k (LP async16 per wave)
  auto stage = [&](int pan, int k) {
#pragma unroll
    for (int i2 = 0; i2 < AI; i2++) async16(aG[i2] + k, aL[i2] + pan * APAN);
#pragma unroll
    for (int i2 = 0; i2 < BI; i2++) async16(bG[i2] + k, bL[i2] + pan * BPAN);
  };

  f32x4 acc[FI][FJ] = {};

  // prologue: depth-2 prefetch
  stage(0, 0);
  if (nt > 1) stage(1, 32);

  int pc = 0, ps = 2;                             // current / stage-ahead panel
  for (int tt = 0; tt < nt; ++tt) {
    if (tt + 2 < nt) { stage(ps, (tt + 2) * 32); waitvm<2 * LP>(); }
    else if (tt + 1 < nt) waitvm<LP>();
    else waitvm<0>();
    __builtin_amdgcn_s_barrier();                 // panel pc ready (all waves)
    __builtin_amdgcn_sched_barrier(0);            // pin ds_reads below barrier

    s16x8 af[FI], bfr[FJ];
#pragma unroll
    for (int i = 0; i < FI; i++) af[i]  = *(const s16x8*)&As[pc * APAN + aOff[i]];
#pragma unroll
    for (int j = 0; j < FJ; j++) bfr[j] = *(const s16x8*)&Bs[pc * BPAN + bOff[j]];

    __builtin_amdgcn_s_setprio(1);
#pragma unroll
    for (int i = 0; i < FI; i++)
#pragma unroll
      for (int j = 0; j < FJ; j++)
        acc[i][j] = __builtin_amdgcn_mfma_f32_16x16x32_bf16(af[i], bfr[j], acc[i][j], 0, 0, 0);
    __builtin_amdgcn_s_setprio(0);

    __builtin_amdgcn_s_barrier();                 // all reads of pc done -> reusable
    pc = (pc == 2) ? 0 : pc + 1;
    ps = (ps == 2) ? 0 : ps + 1;
  }

  // Epilogue. C/D layout (m89/m91): col = lane&15, row = (lane>>4)*4 + reg.
  float* Cf = (float*)Cv;
  bfu*   Cb = (bfu*)Cv;
#pragma unroll
  for (int i = 0; i < FI; i++) {
    const int row0 = tM + wr * FI * 16 + i * 16 + q * 4;
#pragma unroll
    for (int j = 0; j < FJ; j++) {
      const int col = tN + wc * FJ * 16 + j * 16 + l16;
      float cbv = 0.0f;
      if (BIAS == 1) cbv = bias[col];
#pragma unroll
      for (int r = 0; r < 4; r++) {
        float v = acc[i][j][r];
        if (CAUSAL) { v *= scale; if (col > row0 + r) v = -1e30f; }
        if (BIAS == 1) v += cbv;
        if (BIAS == 2) v += bias[row0 + r];
        if (RELU) v = fmaxf(v, 0.0f);
        long idxc = cBase + (long)(row0 + r) * ldc + col;
        if (OUT_BF16) Cb[idxc] = f2b(v); else Cf[idxc] = v;
      }
    }
  }
}

// ---------------------------------------------------------------------------
// fp32 [R,C] -> bf16 [C,R] transpose+convert (used for W_out)
// pad 66: transposed-read bank stride 33 -> conflict-free
// ---------------------------------------------------------------------------
__global__ void transpose_cvt(const float* __restrict__ src, bfu* __restrict__ dst,
                              int R, int C)
{
  __shared__ bfu tile[64 * 66];
  const int t = threadIdx.x;
  const int tc = blockIdx.x * 64, tr = blockIdx.y * 64;
#pragma unroll
  for (int i = 0; i < 16; i++) {
    int idx = t + i * 256; int r = idx >> 6, c = idx & 63;
    tile[r * 66 + c] = f2b(src[(long)(tr + r) * C + tc + c]);
  }
  __syncthreads();
#pragma unroll
  for (int i = 0; i < 16; i++) {
    int idx = t + i * 256; int r = idx >> 6, c = idx & 63;
    dst[(long)(tc + r) * R + tr + c] = tile[c * 66 + r];
  }
}

// ---------------------------------------------------------------------------
// Fused per-layer weight prep (transposes + q|k bias pack). 2592 blocks.
// ---------------------------------------------------------------------------
__global__ void prep_layer(const float* __restrict__ Wq, const float* __restrict__ Wk,
                           const float* __restrict__ Wv, const float* __restrict__ Wo,
                           const float* __restrict__ W1, const float* __restrict__ W2,
                           const float* __restrict__ bq, const float* __restrict__ bk,
                           bfu* __restrict__ qkvwT, bfu* __restrict__ woT,
                           bfu* __restrict__ w1T, bfu* __restrict__ w2T,
                           float* __restrict__ qkb)
{
  const int bid = blockIdx.x;
  const int t = threadIdx.x;

  if (bid >= 2560) {                        // bias pack: 8192 elems, 32 blocks
    int j = (bid - 2560) * 256 + t;
    qkb[j] = (j < 4096) ? bq[j] : bk[j - 4096];
    return;
  }

  const float* src; bfu* dst; int R, C, ctiles, local;
  if (bid < 512)       { src = Wq; dst = qkvwT;              R = 512;  C = 4096; ctiles = 64; local = bid; }
  else if (bid < 1024) { src = Wk; dst = qkvwT + 4096L*512;  R = 512;  C = 4096; ctiles = 64; local = bid - 512; }
  else if (bid < 1536) { src = Wv; dst = qkvwT + 8192L*512;  R = 512;  C = 4096; ctiles = 64; local = bid - 1024; }
  else if (bid < 2048) { src = Wo; dst = woT;                R = 4096; C = 512;  ctiles = 8;  local = bid - 1536; }
  else if (bid < 2304) { src = W1; dst = w1T;                R = 512;  C = 2048; ctiles = 32; local = bid - 2048; }
  else                 { src = W2; dst = w2T;                R = 2048; C = 512;  ctiles = 8;  local = bid - 2304; }
  const int tc = (local % ctiles) * 64;
  const int tr = (local / ctiles) * 64;

  __shared__ bfu tile[64 * 66];
#pragma unroll
  for (int i = 0; i < 16; i++) {
    int idx = t + i * 256; int r = idx >> 6, c = idx & 63;
    tile[r * 66 + c] = f2b(src[(long)(tr + r) * C + tc + c]);
  }
  __syncthreads();
#pragma unroll
  for (int i = 0; i < 16; i++) {
    int idx = t + i * 256; int r = idx >> 6, c = idx & 63;
    dst[(long)(tc + r) * R + tr + c] = tile[c * 66 + r];
  }
}

// block (256 threads) stats over 512 values (2/thread pre-summed by caller)
__device__ __forceinline__ void blk_stats(float s, float ss, float* red,
                                          float& mean, float& var)
{
#pragma unroll
  for (int off = 32; off; off >>= 1) { s += __shfl_down(s, off); ss += __shfl_down(ss, off); }
  int w = threadIdx.x >> 6;
  if ((threadIdx.x & 63) == 0) { red[w] = s; red[4 + w] = ss; }
  __syncthreads();
  s  = red[0] + red[1] + red[2] + red[3];
  ss = red[4] + red[5] + red[6] + red[7];
  mean = s * (1.0f / 512.0f);
  var  = ss * (1.0f / 512.0f) - mean * mean;
}

__global__ void embed_ln(const int* __restrict__ ids, const float* __restrict__ tok,
                         const float* __restrict__ pos, const float* __restrict__ g,
                         const float* __restrict__ bta, float* __restrict__ h,
                         bfu* __restrict__ hb)
{
  __shared__ float red[8];
  const int row = blockIdx.x;          // b*S + s
  const int s = row & 1023;
  const int t = threadIdx.x;
  const long base = (long)row * 512;
  const int id = ids[row];
  float x0 = tok[(long)id * 512 + t]       + pos[(long)s * 512 + t];
  float x1 = tok[(long)id * 512 + t + 256] + pos[(long)s * 512 + t + 256];
  float mean, var;
  blk_stats(x0 + x1, x0 * x0 + x1 * x1, red, mean, var);
  float rstd = rsqrtf(var + 1e-5f);
  float y0 = (x0 - mean) * rstd * g[t]       + bta[t];
  float y1 = (x1 - mean) * rstd * g[t + 256] + bta[t + 256];
  h[base + t] = y0;        h[base + t + 256] = y1;
  hb[base + t] = f2b(y0);  hb[base + t + 256] = f2b(y1);
}

// x = sum_{s<n} p[i+s*ps] + bias[col] + h[i] -> LN -> h, hb
__global__ void add_ln_redN(const float* __restrict__ p, long ps, int n,
                            const float* __restrict__ bias,
                            float* __restrict__ h, bfu* __restrict__ hb,
                            const float* __restrict__ g, const float* __restrict__ bta)
{
  __shared__ float red[8];
  const long base = (long)blockIdx.x * 512;
  const int t = threadIdx.x;
  float x0 = bias[t]       + h[base + t];
  float x1 = bias[t + 256] + h[base + t + 256];
  for (int s = 0; s < n; s++) {
    x0 += p[base + (long)s * ps + t];
    x1 += p[base + (long)s * ps + t + 256];
  }
  float mean, var;
  blk_stats(x0 + x1, x0 * x0 + x1 * x1, red, mean, var);
  float rstd = rsqrtf(var + 1e-5f);
  float y0 = (x0 - mean) * rstd * g[t]       + bta[t];
  float y1 = (x1 - mean) * rstd * g[t + 256] + bta[t + 256];
  h[base + t] = y0;        h[base + t + 256] = y1;
  hb[base + t] = f2b(y0);  hb[base + t + 256] = f2b(y1);
}

// out[i] = sum_{s<n} p[i+s*ps] + bias[col]
__global__ void out_redN(const float* __restrict__ p, long ps, int n,
                         const float* __restrict__ bias, float* __restrict__ out)
{
  const long base = (long)blockIdx.x * 512;
  const int t = threadIdx.x;
  float x0 = bias[t], x1 = bias[t + 256];
  for (int s = 0; s < n; s++) {
    x0 += p[base + (long)s * ps + t];
    x1 += p[base + (long)s * ps + t + 256];
  }
  out[base + t] = x0;
  out[base + t + 256] = x1;
}

// Causal in-place softmax, row r = blockIdx.x & 1023 of a 1024-wide bf16 row.
// Vectorized: thread t owns 4 contiguous cols (u16x4 load/store).
// Reads cols <= r only (others masked); writes cols < roundup128(r+1).
__global__ void softmax_causal(bfu* __restrict__ P)
{
  __shared__ float red[8];
  const long base = (long)blockIdx.x * 1024;
  const int r = blockIdx.x & 1023;
  const int wlim = ((r >> 7) + 1) << 7;          // multiple of 128 (and of 4)
  const int t = threadIdx.x;
  const int c0 = t * 4;
  u16x4 pk = *(const u16x4*)&P[base + c0];
  float v[4];
  float mx = -3e30f;
#pragma unroll
  for (int i = 0; i < 4; i++) {
    const int col = c0 + i;
    v[i] = (col <= r) ? b2f(pk[i]) : -3e30f;
    mx = fmaxf(mx, v[i]);
  }
#pragma unroll
  for (int off = 32; off; off >>= 1) mx = fmaxf(mx, __shfl_xor(mx, off));
  int w = t >> 6;
  if ((t & 63) == 0) red[w] = mx;
  __syncthreads();
  mx = fmaxf(fmaxf(red[0], red[1]), fmaxf(red[2], red[3]));
  float e[4], sum = 0.0f;
#pragma unroll
  for (int i = 0; i < 4; i++) {
    const int col = c0 + i;
    e[i] = (col <= r) ? expf(v[i] - mx) : 0.0f;
    sum += e[i];
  }
#pragma unroll
  for (int off = 32; off; off >>= 1) sum += __shfl_xor(sum, off);
  __syncthreads();
  if ((t & 63) == 0) red[4 + w] = sum;
  __syncthreads();
  sum = red[4] + red[5] + red[6] + red[7];
  float inv = 1.0f / sum;
  if (c0 < wlim) {
    u16x4 o;
#pragma unroll
    for (int i = 0; i < 4; i++) o[i] = f2b(e[i] * inv);
    *(u16x4*)&P[base + c0] = o;
  }
}

// ---------------------------------------------------------------------------
extern "C" void kernel_launch(void* const* d_in, const int* in_sizes, int n_in,
                              void* d_out, int out_size, void* d_ws, size_t ws_size,
                              hipStream_t stream)
{
  const int*   x     = (const int*)  d_in[0];
  const float* tok   = (const float*)d_in[1];
  const float* pos   = (const float*)d_in[2];
  const float* lnig  = (const float*)d_in[3];
  const float* lnib  = (const float*)d_in[4];
  const float* Wq    = (const float*)d_in[5];
  const float* bq    = (const float*)d_in[6];
  const float* Wk    = (const float*)d_in[7];
  const float* bk    = (const float*)d_in[8];
  const float* Wv    = (const float*)d_in[9];
  const float* bv    = (const float*)d_in[10];
  const float* Wo    = (const float*)d_in[11];
  const float* bo    = (const float*)d_in[12];
  const float* ln1g  = (const float*)d_in[13];
  const float* ln1b  = (const float*)d_in[14];
  const float* W1    = (const float*)d_in[15];
  const float* b1    = (const float*)d_in[16];
  const float* W2    = (const float*)d_in[17];
  const float* b2    = (const float*)d_in[18];
  const float* ln2g  = (const float*)d_in[19];
  const float* ln2b  = (const float*)d_in[20];
  const float* Wout  = (const float*)d_in[21];
  const float* bout  = (const float*)d_in[22];

  // ---- workspace tiering (deterministic in ws_size) ----
  const size_t MB = 1024 * 1024;
  int gb; bool s4;                           // batches per attention group; split-K=4 path
  if      (ws_size >= 236 * MB) { gb = 4; s4 = true;  }
  else if (ws_size >= 169 * MB) { gb = 2; s4 = true;  }
  else if (ws_size >= 152 * MB) { gb = 1; s4 = true;  }
  else                          { gb = 1; s4 = false; }   // == round-4 layout (~110 MB)

  const size_t qkBytes = (size_t)gb * 1024 * 8192 * 2;
  const size_t scB0    = (size_t)gb * 8 * 1024 * 1024 * 2;
  const size_t scBytes = s4 ? (scB0 > 33554432 ? scB0 : 33554432) : 16777216;
  const size_t vtB0    = (size_t)gb * 8 * 512 * 1024 * 2;
  const size_t vtBytes = s4 ? (vtB0 > 33554432 ? vtB0 : 33554432) : 8388608;

  char* wsp = (char*)d_ws;
  auto alloc = [&](size_t bytes) { char* p = wsp; wsp += (bytes + 255) & ~(size_t)255; return p; };

  bfu*   qkvwT = (bfu*)  alloc(12288L * 512 * 2);
  bfu*   woT   = (bfu*)  alloc(512L * 4096 * 2);
  bfu*   w1T   = (bfu*)  alloc(2048L * 512 * 2);
  bfu*   w2T   = (bfu*)  alloc(512L * 2048 * 2);
  bfu*   woutT = (bfu*)  alloc(512L * 512 * 2);
  float* qkb   = (float*)alloc(8192L * 4);
  float* h     = (float*)alloc(4096L * 512 * 4);        // fp32 residual stream
  bfu*   hb    = (bfu*)  alloc(4096L * 512 * 2);        // bf16 copy (GEMM A operand)
  bfu*   attn  = (bfu*)  alloc(4096L * 4096 * 2);       // attention out, all tokens
  bfu*   qkS   = (bfu*)  alloc(qkBytes);                // q|k group; (!s4) FFN2/final partials
  bfu*   scS   = (bfu*)  alloc(scBytes);                // scores; Wo partials; FFN hidden
  bfu*   vTS   = (bfu*)  alloc(vtBytes);                // v^T group; (s4) FFN2/final partials

  float* pWo = (float*)scS;
  float* pF  = s4 ? (float*)vTS : (float*)qkS;
  const int nspl = s4 ? 4 : 2;

  embed_ln<<<4096, 256, 0, stream>>>(x, tok, pos, lnig, lnib, h, hb);
  transpose_cvt<<<dim3(8, 8), 256, 0, stream>>>(Wout, woutT, 512, 512);

  const float invsq = 0.044194173824159216f;  // 1/sqrt(512)
  const long  PSTR  = 4096L * 512;            // split-K partial stride (floats)

  for (int l = 0; l < 6; l++) {
    prep_layer<<<2592, 256, 0, stream>>>(
        Wq + (long)l*512*4096, Wk + (long)l*512*4096, Wv + (long)l*512*4096,
        Wo + (long)l*4096*512, W1 + (long)l*512*2048, W2 + (long)l*2048*512,
        bq + (long)l*4096, bk + (long)l*4096,
        qkvwT, woT, w1T, w2T, qkb);

    for (int g0 = 0; g0 < 4; g0 += gb) {
      const bfu* hbG = hb + (long)g0 * 1024 * 512;

      // q|k: [gb*1024,512] x [8192,512]^T -> qkS (+col bias)
      gemm_bt<128,128,2,2,4,4,true,false,false,1,false>
          <<<dim3(64, gb*8, 1), 256, 0, stream>>>(
          hbG, 512, 0, 0, qkvwT, 512, 0, 0, qkS, 8192, 0, 0,
          qkb, 512, 1, 1.0f, 8);

      // vT[b][h][d][s] = Wv^T @ h_b^T (+row bias): z = batch
      gemm_bt<128,128,2,2,4,4,true,false,false,2,false>
          <<<dim3(8, 32, gb), 256, 0, stream>>>(
          qkvwT + 8192L*512, 512, 0, 0,
          hbG, 512, 0, 1024L*512,
          vTS, 1024, 0, 4096L*1024,
          bv + (long)l*4096, 512, gb, 1.0f, 8);

      // scores = (q k^T)/sqrt(dh), causal (upper tiles skipped): z = b*8+h
      gemm_bt<128,128,2,2,4,4,true,false,true,0,false>
          <<<dim3(8, 8, gb*8), 256, 0, stream>>>(
          qkS,        8192, 1024L*8192, 512,
          qkS + 4096, 8192, 1024L*8192, 512,
          scS, 1024, 8L*1024*1024, 1024L*1024,
          nullptr, 512, 8, invsq, 8);

      softmax_causal<<<gb*8192, 256, 0, stream>>>(scS);

      // attn = P @ v, triangular K, 128x128 tile (cx=4): z = b*8+h
      gemm_bt<128,128,2,2,4,4,true,false,false,0,true>
          <<<dim3(4, 8, gb*8), 256, 0, stream>>>(
          scS, 1024, 8L*1024*1024, 1024L*1024,
          vTS, 1024, 8L*512*1024,  512L*1024,
          attn + (long)g0*1024*4096, 4096, 1024L*4096, 512,
          nullptr, 1024, 8, 1.0f, 4);
    }

    // Wo projection -> fp32 partials
    if (s4) {
      gemm_bt<128,128,2,2,4,4,false,false,false,0,false>
          <<<dim3(4, 32, 4), 256, 0, stream>>>(
          attn, 4096, 0, 1024, woT, 4096, 0, 1024,
          pWo, 512, 0, PSTR, nullptr, 1024, 4, 1.0f, 4);
    } else {
      gemm_bt<128,64,2,2,4,2,false,false,false,0,false>
          <<<dim3(8, 32, 2), 256, 0, stream>>>(
          attn, 4096, 0, 2048, woT, 4096, 0, 2048,
          pWo, 512, 0, PSTR, nullptr, 2048, 1, 1.0f, 8);
    }
    add_ln_redN<<<4096, 256, 0, stream>>>(pWo, PSTR, nspl, bo + (long)l*512,
                                          h, hb, ln1g + (long)l*512, ln1b + (long)l*512);

    // FFN1 (+ReLU) -> bf16 hidden in scS [4096,2048]
    gemm_bt<128,128,2,2,4,4,true,true,false,1,false>
        <<<dim3(16, 32, 1), 256, 0, stream>>>(
        hb, 512, 0, 0, w1T, 512, 0, 0, scS, 2048, 0, 0,
        b1 + (long)l*2048, 512, 1, 1.0f, 16);

    // FFN2 -> fp32 partials
    if (s4) {
      gemm_bt<128,128,2,2,4,4,false,false,false,0,false>
          <<<dim3(4, 32, 4), 256, 0, stream>>>(
          scS, 2048, 0, 512, w2T, 2048, 0, 512,
          pF, 512, 0, PSTR, nullptr, 512, 4, 1.0f, 4);
    } else {
      gemm_bt<128,64,2,2,4,2,false,false,false,0,false>
          <<<dim3(8, 32, 2), 256, 0, stream>>>(
          scS, 2048, 0, 1024, w2T, 2048, 0, 1024,
          pF, 512, 0, PSTR, nullptr, 1024, 1, 1.0f, 8);
    }
    add_ln_redN<<<4096, 256, 0, stream>>>(pF, PSTR, nspl, b2 + (long)l*512,
                                          h, hb, ln2g + (long)l*512, ln2b + (long)l*512);
  }

  // final projection (K=128 per split: multiple of 64 ✓)
  if (s4) {
    gemm_bt<128,128,2,2,4,4,false,false,false,0,false>
        <<<dim3(4, 32, 4), 256, 0, stream>>>(
        hb, 512, 0, 128, woutT, 512, 0, 128,
        pF, 512, 0, PSTR, nullptr, 128, 4, 1.0f, 4);
  } else {
    gemm_bt<128,64,2,2,4,2,false,false,false,0,false>
        <<<dim3(8, 32, 2), 256, 0, stream>>>(
        hb, 512, 0, 256, woutT, 512, 0, 256,
        pF, 512, 0, PSTR, nullptr, 256, 1, 1.0f, 8);
  }
  out_redN<<<4096, 256, 0, stream>>>(pF, PSTR, nspl, bout, (float*)d_out);
}

// Round 12
// 1897.609 us; speedup vs baseline: 1.0976x; 1.0228x over previous
//
#include <hip/hip_runtime.h>
#include <math.h>

// AutoregressiveTransformer on MI355X (gfx950).
// Round 11: merge of the two verified K-loop cores, deployed by occupancy
// regime (r6-r10 ledger):
//  - NPAN=3: 3-panel, 2-barrier, 48KB (3 blocks/CU) -- best for q|k
//    (2048-block dispatches; proven 55.7us vs 63.9 with 4-panel).
//  - NPAN=4: 4-panel, 1-barrier, 64KB -- best for the <=2-blocks/CU
//    dispatches (split-K Wo/FFN2/final, FFN1, and the rest of the r8
//    config that measured 1926.3 total).
// Plus round-8 vectorized softmax and round-10 pad-66 transposes.

typedef unsigned short bfu;                                  // raw bf16 bits
typedef short  s16x8 __attribute__((ext_vector_type(8)));    // 8 bf16 = 4 VGPR
typedef float  f32x4 __attribute__((ext_vector_type(4)));    // MFMA C/D frag
typedef unsigned short u16x4 __attribute__((ext_vector_type(4)));

__device__ __forceinline__ bfu f2b(float f) {                // fp32 -> bf16 (RNE)
  unsigned int u = __float_as_uint(f);
  unsigned int r = (u + 0x7fffu + ((u >> 16) & 1u)) >> 16;
  return (bfu)r;
}
__device__ __forceinline__ float b2f(bfu h) {
  return __uint_as_float(((unsigned int)h) << 16);
}

// async global->LDS, 16 B per lane; LDS dest = wave-uniform base + lane*16
__device__ __forceinline__ void async16(const bfu* g, bfu* l) {
  __builtin_amdgcn_global_load_lds(
      (const __attribute__((address_space(1))) void*)g,
      (__attribute__((address_space(3))) void*)l, 16, 0, 0);
}

// counted vmcnt wait (literal immediates only)
template<int N> __device__ __forceinline__ void waitvm() {
  static_assert(N == 0 || N == 3 || N == 4 || N == 6 || N == 8, "vmcnt imm");
  if constexpr      (N == 0) asm volatile("s_waitcnt vmcnt(0)" ::: "memory");
  else if constexpr (N == 3) asm volatile("s_waitcnt vmcnt(3)" ::: "memory");
  else if constexpr (N == 4) asm volatile("s_waitcnt vmcnt(4)" ::: "memory");
  else if constexpr (N == 6) asm volatile("s_waitcnt vmcnt(6)" ::: "memory");
  else                       asm volatile("s_waitcnt vmcnt(8)" ::: "memory");
}

// ---------------------------------------------------------------------------
// GEMM: C[m,n] = sum_k A[m,k] * Bt[n,k]  (both K-contiguous), bf16 in, fp32 acc.
// Tile TM x TN = (WY*FI*16) x (WX*FJ*16), WY*WX waves. BK=32 LDS panels.
// NPAN=3 (r7-verified): rotating 3-buffer, depth-2 prefetch, 2 barriers/iter:
//   stage(t+2) ; vmcnt(2LP) ; s_barrier ; ds_read+MFMA ; s_barrier
// NPAN=4 (r8-verified): 4-buffer (t&3), depth-2 prefetch, 1 barrier/iter --
//   stage target (t+2)&3 was read at t-2, two program-order barriers ago.
// Steady-state never drains vmcnt to 0 in either core. R4-proven XOR
// column-group swizzle (SQ_LDS_BANK_CONFLICT=0). XCD-cluster block swizzle.
// Two-level z for batch/head/split-K. CAUSAL: scale+mask epilogue +
// early-exit above diagonal. TRIK: K clamped to tM+TM. BIAS: 0/1 col/2 row.
// Requires K % 64 == 0 (all call sites satisfy; nt >= 4 everywhere).
// ---------------------------------------------------------------------------
template<int TM, int TN, int WY, int WX, int FI, int FJ,
         bool OUT_BF16, bool RELU, bool CAUSAL, int BIAS, bool TRIK, int NPAN>
__global__ __launch_bounds__(WY * WX * 64)
void gemm_bt(const bfu* __restrict__ A, long lda, long sAo, long sAi,
             const bfu* __restrict__ B, long ldb, long sBo, long sBi,
             void* __restrict__ Cv, long ldc, long sCo, long sCi,
             const float* __restrict__ bias,
             int K, int zInner, float scale, int cx)
{
  static_assert(TM == WY * FI * 16 && TN == WX * FJ * 16, "tile mismatch");
  static_assert(NPAN == 3 || NPAN == 4, "panel count");
  constexpr int NW = WY * WX;
  constexpr int AI = TM / (16 * NW);              // A staging instrs/wave/panel
  constexpr int BI = TN / (16 * NW);              // B staging instrs/wave/panel
  constexpr int LP = AI + BI;                     // loads/wave/panel
  constexpr int APAN = TM * 32;                   // panel stride (elements)
  constexpr int BPAN = TN * 32;

  __shared__ __align__(16) bfu As[NPAN * APAN];
  __shared__ __align__(16) bfu Bs[NPAN * BPAN];

  // ---- XCD-cluster tile decode (total%8==0, cx|NX, cx|perX) ----
  const int NX = gridDim.x, NY = gridDim.y;
  const int flat  = blockIdx.x + NX * (blockIdx.y + NY * blockIdx.z);
  const int total = NX * NY * gridDim.z;
  const int xcd = flat & 7, idx = flat >> 3;
  const int perX = total >> 3;
  const int clX  = NX / cx;
  const int ry   = perX / cx;
  const int tx   = (xcd % clX) * cx + idx % cx;
  const int yz   = (xcd / clX) * ry + idx / cx;
  const int ty   = yz % NY, tz = yz / NY;

  const int tM = ty * TM;
  const int tN = tx * TN;
  if (CAUSAL && tN >= tM + TM) return;            // fully-masked tile

  const int zo = tz / zInner, zi = tz - zo * zInner;
  A += (long)zo * sAo + (long)zi * sAi;
  B += (long)zo * sBo + (long)zi * sBi;
  const long cBase = (long)zo * sCo + (long)zi * sCi;

  const int t = threadIdx.x;
  const int wave = t >> 6, lane = t & 63;
  const int wr = wave / WX, wc = wave % WX;
  const int q = lane >> 4, l16 = lane & 15;

  // ---- staging addresses (lane -> row lane/4, col-group (lane&3)^swz(row)) ----
  const bfu* aG[AI]; bfu* aL[AI];
  const bfu* bG[BI]; bfu* bL[BI];
#pragma unroll
  for (int i2 = 0; i2 < AI; i2++) {
    const int rb = (i2 * NW + wave) * 16;
    const int r  = rb + (lane >> 2);
    const int g  = (lane & 3) ^ ((r >> 1) & 3);
    aG[i2] = A + (long)(tM + r) * lda + g * 8;
    aL[i2] = &As[rb * 32];
  }
#pragma unroll
  for (int i2 = 0; i2 < BI; i2++) {
    const int rb = (i2 * NW + wave) * 16;
    const int r  = rb + (lane >> 2);
    const int g  = (lane & 3) ^ ((r >> 1) & 3);
    bG[i2] = B + (long)(tN + r) * ldb + g * 8;
    bL[i2] = &Bs[rb * 32];
  }

  // ---- fragment LDS offsets (swizzled; k-invariant, per panel) ----
  int aOff[FI], bOff[FJ];
#pragma unroll
  for (int i = 0; i < FI; i++) {
    const int r = wr * FI * 16 + i * 16 + l16;
    aOff[i] = r * 32 + ((q ^ ((r >> 1) & 3)) * 8);
  }
#pragma unroll
  for (int j = 0; j < FJ; j++) {
    const int r = wc * FJ * 16 + j * 16 + l16;
    bOff[j] = r * 32 + ((q ^ ((r >> 1) & 3)) * 8);
  }

  const int Kend = TRIK ? ((tM + TM < K) ? tM + TM : K) : K;
  const int nt   = Kend >> 5;                     // BK=32 stages (>= 4)

  // stage panel pan with K-offset k (LP async16 per wave)
  auto stage = [&](int pan, int k) {
#pragma unroll
    for (int i2 = 0; i2 < AI; i2++) async16(aG[i2] + k, aL[i2] + pan * APAN);
#pragma unroll
    for (int i2 = 0; i2 < BI; i2++) async16(bG[i2] + k, bL[i2] + pan * BPAN);
  };

  f32x4 acc[FI][FJ] = {};

  // compute one staged panel from LDS
  auto compute = [&](int pan) {
    s16x8 af[FI], bfr[FJ];
#pragma unroll
    for (int i = 0; i < FI; i++) af[i]  = *(const s16x8*)&As[pan * APAN + aOff[i]];
#pragma unroll
    for (int j = 0; j < FJ; j++) bfr[j] = *(const s16x8*)&Bs[pan * BPAN + bOff[j]];
    __builtin_amdgcn_s_setprio(1);
#pragma unroll
    for (int i = 0; i < FI; i++)
#pragma unroll
      for (int j = 0; j < FJ; j++)
        acc[i][j] = __builtin_amdgcn_mfma_f32_16x16x32_bf16(af[i], bfr[j], acc[i][j], 0, 0, 0);
    __builtin_amdgcn_s_setprio(0);
  };

  // prologue: depth-2 prefetch (nt >= 4 at all call sites)
  stage(0, 0);
  stage(1, 32);

  if constexpr (NPAN == 3) {
    int pc = 0, ps = 2;                           // current / stage-ahead panel
    for (int tt = 0; tt < nt; ++tt) {
      if (tt + 2 < nt) { stage(ps, (tt + 2) * 32); waitvm<2 * LP>(); }
      else if (tt + 1 < nt) waitvm<LP>();
      else waitvm<0>();
      __builtin_amdgcn_s_barrier();               // panel pc ready (all waves)
      __builtin_amdgcn_sched_barrier(0);          // pin ds_reads below barrier
      compute(pc);
      __builtin_amdgcn_s_barrier();               // reads of pc done -> reusable
      pc = (pc == 2) ? 0 : pc + 1;
      ps = (ps == 2) ? 0 : ps + 1;
    }
  } else {
    for (int tt = 0; tt < nt; ++tt) {
      const int pc = tt & 3;
      if (tt + 2 < nt) { stage((tt + 2) & 3, (tt + 2) * 32); waitvm<2 * LP>(); }
      else if (tt + 1 < nt) waitvm<LP>();
      else waitvm<0>();
      __builtin_amdgcn_s_barrier();               // panel pc staged (all waves)
      __builtin_amdgcn_sched_barrier(0);          // pin ds_reads below barrier
      compute(pc);
    }
  }

  // Epilogue. C/D layout (m89/m91): col = lane&15, row = (lane>>4)*4 + reg.
  float* Cf = (float*)Cv;
  bfu*   Cb = (bfu*)Cv;
#pragma unroll
  for (int i = 0; i < FI; i++) {
    const int row0 = tM + wr * FI * 16 + i * 16 + q * 4;
#pragma unroll
    for (int j = 0; j < FJ; j++) {
      const int col = tN + wc * FJ * 16 + j * 16 + l16;
      float cbv = 0.0f;
      if (BIAS == 1) cbv = bias[col];
#pragma unroll
      for (int r = 0; r < 4; r++) {
        float v = acc[i][j][r];
        if (CAUSAL) { v *= scale; if (col > row0 + r) v = -1e30f; }
        if (BIAS == 1) v += cbv;
        if (BIAS == 2) v += bias[row0 + r];
        if (RELU) v = fmaxf(v, 0.0f);
        long idxc = cBase + (long)(row0 + r) * ldc + col;
        if (OUT_BF16) Cb[idxc] = f2b(v); else Cf[idxc] = v;
      }
    }
  }
}

// ---------------------------------------------------------------------------
// fp32 [R,C] -> bf16 [C,R] transpose+convert (used for W_out)
// pad 66: transposed-read bank stride 33 -> conflict-free
// ---------------------------------------------------------------------------
__global__ void transpose_cvt(const float* __restrict__ src, bfu* __restrict__ dst,
                              int R, int C)
{
  __shared__ bfu tile[64 * 66];
  const int t = threadIdx.x;
  const int tc = blockIdx.x * 64, tr = blockIdx.y * 64;
#pragma unroll
  for (int i = 0; i < 16; i++) {
    int idx = t + i * 256; int r = idx >> 6, c = idx & 63;
    tile[r * 66 + c] = f2b(src[(long)(tr + r) * C + tc + c]);
  }
  __syncthreads();
#pragma unroll
  for (int i = 0; i < 16; i++) {
    int idx = t + i * 256; int r = idx >> 6, c = idx & 63;
    dst[(long)(tc + r) * R + tr + c] = tile[c * 66 + r];
  }
}

// ---------------------------------------------------------------------------
// Fused per-layer weight prep (transposes + q|k bias pack). 2592 blocks.
// ---------------------------------------------------------------------------
__global__ void prep_layer(const float* __restrict__ Wq, const float* __restrict__ Wk,
                           const float* __restrict__ Wv, const float* __restrict__ Wo,
                           const float* __restrict__ W1, const float* __restrict__ W2,
                           const float* __restrict__ bq, const float* __restrict__ bk,
                           bfu* __restrict__ qkvwT, bfu* __restrict__ woT,
                           bfu* __restrict__ w1T, bfu* __restrict__ w2T,
                           float* __restrict__ qkb)
{
  const int bid = blockIdx.x;
  const int t = threadIdx.x;

  if (bid >= 2560) {                        // bias pack: 8192 elems, 32 blocks
    int j = (bid - 2560) * 256 + t;
    qkb[j] = (j < 4096) ? bq[j] : bk[j - 4096];
    return;
  }

  const float* src; bfu* dst; int R, C, ctiles, local;
  if (bid < 512)       { src = Wq; dst = qkvwT;              R = 512;  C = 4096; ctiles = 64; local = bid; }
  else if (bid < 1024) { src = Wk; dst = qkvwT + 4096L*512;  R = 512;  C = 4096; ctiles = 64; local = bid - 512; }
  else if (bid < 1536) { src = Wv; dst = qkvwT + 8192L*512;  R = 512;  C = 4096; ctiles = 64; local = bid - 1024; }
  else if (bid < 2048) { src = Wo; dst = woT;                R = 4096; C = 512;  ctiles = 8;  local = bid - 1536; }
  else if (bid < 2304) { src = W1; dst = w1T;                R = 512;  C = 2048; ctiles = 32; local = bid - 2048; }
  else                 { src = W2; dst = w2T;                R = 2048; C = 512;  ctiles = 8;  local = bid - 2304; }
  const int tc = (local % ctiles) * 64;
  const int tr = (local / ctiles) * 64;

  __shared__ bfu tile[64 * 66];
#pragma unroll
  for (int i = 0; i < 16; i++) {
    int idx = t + i * 256; int r = idx >> 6, c = idx & 63;
    tile[r * 66 + c] = f2b(src[(long)(tr + r) * C + tc + c]);
  }
  __syncthreads();
#pragma unroll
  for (int i = 0; i < 16; i++) {
    int idx = t + i * 256; int r = idx >> 6, c = idx & 63;
    dst[(long)(tc + r) * R + tr + c] = tile[c * 66 + r];
  }
}

// block (256 threads) stats over 512 values (2/thread pre-summed by caller)
__device__ __forceinline__ void blk_stats(float s, float ss, float* red,
                                          float& mean, float& var)
{
#pragma unroll
  for (int off = 32; off; off >>= 1) { s += __shfl_down(s, off); ss += __shfl_down(ss, off); }
  int w = threadIdx.x >> 6;
  if ((threadIdx.x & 63) == 0) { red[w] = s; red[4 + w] = ss; }
  __syncthreads();
  s  = red[0] + red[1] + red[2] + red[3];
  ss = red[4] + red[5] + red[6] + red[7];
  mean = s * (1.0f / 512.0f);
  var  = ss * (1.0f / 512.0f) - mean * mean;
}

__global__ void embed_ln(const int* __restrict__ ids, const float* __restrict__ tok,
                         const float* __restrict__ pos, const float* __restrict__ g,
                         const float* __restrict__ bta, float* __restrict__ h,
                         bfu* __restrict__ hb)
{
  __shared__ float red[8];
  const int row = blockIdx.x;          // b*S + s
  const int s = row & 1023;
  const int t = threadIdx.x;
  const long base = (long)row * 512;
  const int id = ids[row];
  float x0 = tok[(long)id * 512 + t]       + pos[(long)s * 512 + t];
  float x1 = tok[(long)id * 512 + t + 256] + pos[(long)s * 512 + t + 256];
  float mean, var;
  blk_stats(x0 + x1, x0 * x0 + x1 * x1, red, mean, var);
  float rstd = rsqrtf(var + 1e-5f);
  float y0 = (x0 - mean) * rstd * g[t]       + bta[t];
  float y1 = (x1 - mean) * rstd * g[t + 256] + bta[t + 256];
  h[base + t] = y0;        h[base + t + 256] = y1;
  hb[base + t] = f2b(y0);  hb[base + t + 256] = f2b(y1);
}

// x = sum_{s<n} p[i+s*ps] + bias[col] + h[i] -> LN -> h, hb
__global__ void add_ln_redN(const float* __restrict__ p, long ps, int n,
                            const float* __restrict__ bias,
                            float* __restrict__ h, bfu* __restrict__ hb,
                            const float* __restrict__ g, const float* __restrict__ bta)
{
  __shared__ float red[8];
  const long base = (long)blockIdx.x * 512;
  const int t = threadIdx.x;
  float x0 = bias[t]       + h[base + t];
  float x1 = bias[t + 256] + h[base + t + 256];
  for (int s = 0; s < n; s++) {
    x0 += p[base + (long)s * ps + t];
    x1 += p[base + (long)s * ps + t + 256];
  }
  float mean, var;
  blk_stats(x0 + x1, x0 * x0 + x1 * x1, red, mean, var);
  float rstd = rsqrtf(var + 1e-5f);
  float y0 = (x0 - mean) * rstd * g[t]       + bta[t];
  float y1 = (x1 - mean) * rstd * g[t + 256] + bta[t + 256];
  h[base + t] = y0;        h[base + t + 256] = y1;
  hb[base + t] = f2b(y0);  hb[base + t + 256] = f2b(y1);
}

// out[i] = sum_{s<n} p[i+s*ps] + bias[col]
__global__ void out_redN(const float* __restrict__ p, long ps, int n,
                         const float* __restrict__ bias, float* __restrict__ out)
{
  const long base = (long)blockIdx.x * 512;
  const int t = threadIdx.x;
  float x0 = bias[t], x1 = bias[t + 256];
  for (int s = 0; s < n; s++) {
    x0 += p[base + (long)s * ps + t];
    x1 += p[base + (long)s * ps + t + 256];
  }
  out[base + t] = x0;
  out[base + t + 256] = x1;
}

// Causal in-place softmax, row r = blockIdx.x & 1023 of a 1024-wide bf16 row.
// Vectorized: thread t owns 4 contiguous cols (u16x4 load/store).
// Reads cols <= r only (others masked); writes cols < roundup128(r+1).
__global__ void softmax_causal(bfu* __restrict__ P)
{
  __shared__ float red[8];
  const long base = (long)blockIdx.x * 1024;
  const int r = blockIdx.x & 1023;
  const int wlim = ((r >> 7) + 1) << 7;          // multiple of 128 (and of 4)
  const int t = threadIdx.x;
  const int c0 = t * 4;
  u16x4 pk = *(const u16x4*)&P[base + c0];
  float v[4];
  float mx = -3e30f;
#pragma unroll
  for (int i = 0; i < 4; i++) {
    const int col = c0 + i;
    v[i] = (col <= r) ? b2f(pk[i]) : -3e30f;
    mx = fmaxf(mx, v[i]);
  }
#pragma unroll
  for (int off = 32; off; off >>= 1) mx = fmaxf(mx, __shfl_xor(mx, off));
  int w = t >> 6;
  if ((t & 63) == 0) red[w] = mx;
  __syncthreads();
  mx = fmaxf(fmaxf(red[0], red[1]), fmaxf(red[2], red[3]));
  float e[4], sum = 0.0f;
#pragma unroll
  for (int i = 0; i < 4; i++) {
    const int col = c0 + i;
    e[i] = (col <= r) ? expf(v[i] - mx) : 0.0f;
    sum += e[i];
  }
#pragma unroll
  for (int off = 32; off; off >>= 1) sum += __shfl_xor(sum, off);
  __syncthreads();
  if ((t & 63) == 0) red[4 + w] = sum;
  __syncthreads();
  sum = red[4] + red[5] + red[6] + red[7];
  float inv = 1.0f / sum;
  if (c0 < wlim) {
    u16x4 o;
#pragma unroll
    for (int i = 0; i < 4; i++) o[i] = f2b(e[i] * inv);
    *(u16x4*)&P[base + c0] = o;
  }
}

// ---------------------------------------------------------------------------
extern "C" void kernel_launch(void* const* d_in, const int* in_sizes, int n_in,
                              void* d_out, int out_size, void* d_ws, size_t ws_size,
                              hipStream_t stream)
{
  const int*   x     = (const int*)  d_in[0];
  const float* tok   = (const float*)d_in[1];
  const float* pos   = (const float*)d_in[2];
  const float* lnig  = (const float*)d_in[3];
  const float* lnib  = (const float*)d_in[4];
  const float* Wq    = (const float*)d_in[5];
  const float* bq    = (const float*)d_in[6];
  const float* Wk    = (const float*)d_in[7];
  const float* bk    = (const float*)d_in[8];
  const float* Wv    = (const float*)d_in[9];
  const float* bv    = (const float*)d_in[10];
  const float* Wo    = (const float*)d_in[11];
  const float* bo    = (const float*)d_in[12];
  const float* ln1g  = (const float*)d_in[13];
  const float* ln1b  = (const float*)d_in[14];
  const float* W1    = (const float*)d_in[15];
  const float* b1    = (const float*)d_in[16];
  const float* W2    = (const float*)d_in[17];
  const float* b2    = (const float*)d_in[18];
  const float* ln2g  = (const float*)d_in[19];
  const float* ln2b  = (const float*)d_in[20];
  const float* Wout  = (const float*)d_in[21];
  const float* bout  = (const float*)d_in[22];

  // ---- workspace tiering (deterministic in ws_size) ----
  const size_t MB = 1024 * 1024;
  int gb; bool s4;                           // batches per attention group; split-K=4 path
  if      (ws_size >= 236 * MB) { gb = 4; s4 = true;  }
  else if (ws_size >= 169 * MB) { gb = 2; s4 = true;  }
  else if (ws_size >= 152 * MB) { gb = 1; s4 = true;  }
  else                          { gb = 1; s4 = false; }   // == round-4 layout (~110 MB)

  const size_t qkBytes = (size_t)gb * 1024 * 8192 * 2;
  const size_t scB0    = (size_t)gb * 8 * 1024 * 1024 * 2;
  const size_t scBytes = s4 ? (scB0 > 33554432 ? scB0 : 33554432) : 16777216;
  const size_t vtB0    = (size_t)gb * 8 * 512 * 1024 * 2;
  const size_t vtBytes = s4 ? (vtB0 > 33554432 ? vtB0 : 33554432) : 8388608;

  char* wsp = (char*)d_ws;
  auto alloc = [&](size_t bytes) { char* p = wsp; wsp += (bytes + 255) & ~(size_t)255; return p; };

  bfu*   qkvwT = (bfu*)  alloc(12288L * 512 * 2);
  bfu*   woT   = (bfu*)  alloc(512L * 4096 * 2);
  bfu*   w1T   = (bfu*)  alloc(2048L * 512 * 2);
  bfu*   w2T   = (bfu*)  alloc(512L * 2048 * 2);
  bfu*   woutT = (bfu*)  alloc(512L * 512 * 2);
  float* qkb   = (float*)alloc(8192L * 4);
  float* h     = (float*)alloc(4096L * 512 * 4);        // fp32 residual stream
  bfu*   hb    = (bfu*)  alloc(4096L * 512 * 2);        // bf16 copy (GEMM A operand)
  bfu*   attn  = (bfu*)  alloc(4096L * 4096 * 2);       // attention out, all tokens
  bfu*   qkS   = (bfu*)  alloc(qkBytes);                // q|k group; (!s4) FFN2/final partials
  bfu*   scS   = (bfu*)  alloc(scBytes);                // scores; Wo partials; FFN hidden
  bfu*   vTS   = (bfu*)  alloc(vtBytes);                // v^T group; (s4) FFN2/final partials

  float* pWo = (float*)scS;
  float* pF  = s4 ? (float*)vTS : (float*)qkS;
  const int nspl = s4 ? 4 : 2;

  embed_ln<<<4096, 256, 0, stream>>>(x, tok, pos, lnig, lnib, h, hb);
  transpose_cvt<<<dim3(8, 8), 256, 0, stream>>>(Wout, woutT, 512, 512);

  const float invsq = 0.044194173824159216f;  // 1/sqrt(512)
  const long  PSTR  = 4096L * 512;            // split-K partial stride (floats)

  for (int l = 0; l < 6; l++) {
    prep_layer<<<2592, 256, 0, stream>>>(
        Wq + (long)l*512*4096, Wk + (long)l*512*4096, Wv + (long)l*512*4096,
        Wo + (long)l*4096*512, W1 + (long)l*512*2048, W2 + (long)l*2048*512,
        bq + (long)l*4096, bk + (long)l*4096,
        qkvwT, woT, w1T, w2T, qkb);

    for (int g0 = 0; g0 < 4; g0 += gb) {
      const bfu* hbG = hb + (long)g0 * 1024 * 512;

      // q|k: [gb*1024,512] x [8192,512]^T -> qkS (+col bias). 3-panel core.
      gemm_bt<128,128,2,2,4,4,true,false,false,1,false,3>
          <<<dim3(64, gb*8, 1), 256, 0, stream>>>(
          hbG, 512, 0, 0, qkvwT, 512, 0, 0, qkS, 8192, 0, 0,
          qkb, 512, 1, 1.0f, 8);

      // vT[b][h][d][s] = Wv^T @ h_b^T (+row bias): z = batch. 4-panel core.
      gemm_bt<128,128,2,2,4,4,true,false,false,2,false,4>
          <<<dim3(8, 32, gb), 256, 0, stream>>>(
          qkvwT + 8192L*512, 512, 0, 0,
          hbG, 512, 0, 1024L*512,
          vTS, 1024, 0, 4096L*1024,
          bv + (long)l*4096, 512, gb, 1.0f, 8);

      // scores = (q k^T)/sqrt(dh), causal (upper tiles skipped): z = b*8+h
      gemm_bt<128,128,2,2,4,4,true,false,true,0,false,4>
          <<<dim3(8, 8, gb*8), 256, 0, stream>>>(
          qkS,        8192, 1024L*8192, 512,
          qkS + 4096, 8192, 1024L*8192, 512,
          scS, 1024, 8L*1024*1024, 1024L*1024,
          nullptr, 512, 8, invsq, 8);

      softmax_causal<<<gb*8192, 256, 0, stream>>>(scS);

      // attn = P @ v, triangular K: z = b*8+h. 4-panel core (r8 config).
      gemm_bt<128,64,2,2,4,2,true,false,false,0,true,4>
          <<<dim3(8, 8, gb*8), 256, 0, stream>>>(
          scS, 1024, 8L*1024*1024, 1024L*1024,
          vTS, 1024, 8L*512*1024,  512L*1024,
          attn + (long)g0*1024*4096, 4096, 1024L*4096, 512,
          nullptr, 1024, 8, 1.0f, 8);
    }

    // Wo projection -> fp32 partials
    if (s4) {
      gemm_bt<128,128,2,2,4,4,false,false,false,0,false,4>
          <<<dim3(4, 32, 4), 256, 0, stream>>>(
          attn, 4096, 0, 1024, woT, 4096, 0, 1024,
          pWo, 512, 0, PSTR, nullptr, 1024, 4, 1.0f, 4);
    } else {
      gemm_bt<128,64,2,2,4,2,false,false,false,0,false,4>
          <<<dim3(8, 32, 2), 256, 0, stream>>>(
          attn, 4096, 0, 2048, woT, 4096, 0, 2048,
          pWo, 512, 0, PSTR, nullptr, 2048, 1, 1.0f, 8);
    }
    add_ln_redN<<<4096, 256, 0, stream>>>(pWo, PSTR, nspl, bo + (long)l*512,
                                          h, hb, ln1g + (long)l*512, ln1b + (long)l*512);

    // FFN1 (+ReLU) -> bf16 hidden in scS [4096,2048]
    gemm_bt<128,128,2,2,4,4,true,true,false,1,false,4>
        <<<dim3(16, 32, 1), 256, 0, stream>>>(
        hb, 512, 0, 0, w1T, 512, 0, 0, scS, 2048, 0, 0,
        b1 + (long)l*2048, 512, 1, 1.0f, 16);

    // FFN2 -> fp32 partials
    if (s4) {
      gemm_bt<128,128,2,2,4,4,false,false,false,0,false,4>
          <<<dim3(4, 32, 4), 256, 0, stream>>>(
          scS, 2048, 0, 512, w2T, 2048, 0, 512,
          pF, 512, 0, PSTR, nullptr, 512, 4, 1.0f, 4);
    } else {
      gemm_bt<128,64,2,2,4,2,false,false,false,0,false,4>
          <<<dim3(8, 32, 2), 256, 0, stream>>>(
          scS, 2048, 0, 1024, w2T, 2048, 0, 1024,
          pF, 512, 0, PSTR, nullptr, 1024, 1, 1.0f, 8);
    }
    add_ln_redN<<<4096, 256, 0, stream>>>(pF, PSTR, nspl, b2 + (long)l*512,
                                          h, hb, ln2g + (long)l*512, ln2b + (long)l*512);
  }

  // final projection (K=128 per split: multiple of 64 ✓)
  if (s4) {
    gemm_bt<128,128,2,2,4,4,false,false,false,0,false,4>
        <<<dim3(4, 32, 4), 256, 0, stream>>>(
        hb, 512, 0, 128, woutT, 512, 0, 128,
        pF, 512, 0, PSTR, nullptr, 128, 4, 1.0f, 4);
  } else {
    gemm_bt<128,64,2,2,4,2,false,false,false,0,false,4>
        <<<dim3(8, 32, 2), 256, 0, stream>>>(
        hb, 512, 0, 256, woutT, 512, 0, 256,
        pF, 512, 0, PSTR, nullptr, 256, 1, 1.0f, 8);
  }
  out_redN<<<4096, 256, 0, stream>>>(pF, PSTR, nspl, bout, (float*)d_out);
}

// Round 13
// 1880.483 us; speedup vs baseline: 1.1076x; 1.0091x over previous
//
#include <hip/hip_runtime.h>
#include <math.h>

// AutoregressiveTransformer on MI355X (gfx950).
// Round 13: NPAN deployment refined per the validated occupancy-regime model
// (r12: 1897.6us, q|k 3-panel confirmed at ~56us):
//  - 2048-block dispatches (q|k, scores, PV) -> NPAN=3 (more blocks/CU:
//    q|k/scores 48KB->3 blk/CU, PV-128x64 36KB->4 blk/CU).
//  - <=1024-block dispatches (vT 1024: 2.0 even rounds; Wo/FFN/final 512)
//    -> NPAN=4 (1-barrier, tail-even).
// Everything else identical to round 12 (vec softmax, pad-66 transposes).

typedef unsigned short bfu;                                  // raw bf16 bits
typedef short  s16x8 __attribute__((ext_vector_type(8)));    // 8 bf16 = 4 VGPR
typedef float  f32x4 __attribute__((ext_vector_type(4)));    // MFMA C/D frag
typedef unsigned short u16x4 __attribute__((ext_vector_type(4)));

__device__ __forceinline__ bfu f2b(float f) {                // fp32 -> bf16 (RNE)
  unsigned int u = __float_as_uint(f);
  unsigned int r = (u + 0x7fffu + ((u >> 16) & 1u)) >> 16;
  return (bfu)r;
}
__device__ __forceinline__ float b2f(bfu h) {
  return __uint_as_float(((unsigned int)h) << 16);
}

// async global->LDS, 16 B per lane; LDS dest = wave-uniform base + lane*16
__device__ __forceinline__ void async16(const bfu* g, bfu* l) {
  __builtin_amdgcn_global_load_lds(
      (const __attribute__((address_space(1))) void*)g,
      (__attribute__((address_space(3))) void*)l, 16, 0, 0);
}

// counted vmcnt wait (literal immediates only)
template<int N> __device__ __forceinline__ void waitvm() {
  static_assert(N == 0 || N == 3 || N == 4 || N == 6 || N == 8, "vmcnt imm");
  if constexpr      (N == 0) asm volatile("s_waitcnt vmcnt(0)" ::: "memory");
  else if constexpr (N == 3) asm volatile("s_waitcnt vmcnt(3)" ::: "memory");
  else if constexpr (N == 4) asm volatile("s_waitcnt vmcnt(4)" ::: "memory");
  else if constexpr (N == 6) asm volatile("s_waitcnt vmcnt(6)" ::: "memory");
  else                       asm volatile("s_waitcnt vmcnt(8)" ::: "memory");
}

// ---------------------------------------------------------------------------
// GEMM: C[m,n] = sum_k A[m,k] * Bt[n,k]  (both K-contiguous), bf16 in, fp32 acc.
// Tile TM x TN = (WY*FI*16) x (WX*FJ*16), WY*WX waves. BK=32 LDS panels.
// NPAN=3 (r7-verified): rotating 3-buffer, depth-2 prefetch, 2 barriers/iter:
//   stage(t+2) ; vmcnt(2LP) ; s_barrier ; ds_read+MFMA ; s_barrier
// NPAN=4 (r8-verified): 4-buffer (t&3), depth-2 prefetch, 1 barrier/iter --
//   stage target (t+2)&3 was read at t-2, two program-order barriers ago.
// Steady-state never drains vmcnt to 0 in either core. R4-proven XOR
// column-group swizzle (SQ_LDS_BANK_CONFLICT=0). XCD-cluster block swizzle.
// Two-level z for batch/head/split-K. CAUSAL: scale+mask epilogue +
// early-exit above diagonal. TRIK: K clamped to tM+TM. BIAS: 0/1 col/2 row.
// Requires K % 64 == 0 (all call sites satisfy; nt >= 4 everywhere).
// ---------------------------------------------------------------------------
template<int TM, int TN, int WY, int WX, int FI, int FJ,
         bool OUT_BF16, bool RELU, bool CAUSAL, int BIAS, bool TRIK, int NPAN>
__global__ __launch_bounds__(WY * WX * 64)
void gemm_bt(const bfu* __restrict__ A, long lda, long sAo, long sAi,
             const bfu* __restrict__ B, long ldb, long sBo, long sBi,
             void* __restrict__ Cv, long ldc, long sCo, long sCi,
             const float* __restrict__ bias,
             int K, int zInner, float scale, int cx)
{
  static_assert(TM == WY * FI * 16 && TN == WX * FJ * 16, "tile mismatch");
  static_assert(NPAN == 3 || NPAN == 4, "panel count");
  constexpr int NW = WY * WX;
  constexpr int AI = TM / (16 * NW);              // A staging instrs/wave/panel
  constexpr int BI = TN / (16 * NW);              // B staging instrs/wave/panel
  constexpr int LP = AI + BI;                     // loads/wave/panel
  constexpr int APAN = TM * 32;                   // panel stride (elements)
  constexpr int BPAN = TN * 32;

  __shared__ __align__(16) bfu As[NPAN * APAN];
  __shared__ __align__(16) bfu Bs[NPAN * BPAN];

  // ---- XCD-cluster tile decode (total%8==0, cx|NX, cx|perX) ----
  const int NX = gridDim.x, NY = gridDim.y;
  const int flat  = blockIdx.x + NX * (blockIdx.y + NY * blockIdx.z);
  const int total = NX * NY * gridDim.z;
  const int xcd = flat & 7, idx = flat >> 3;
  const int perX = total >> 3;
  const int clX  = NX / cx;
  const int ry   = perX / cx;
  const int tx   = (xcd % clX) * cx + idx % cx;
  const int yz   = (xcd / clX) * ry + idx / cx;
  const int ty   = yz % NY, tz = yz / NY;

  const int tM = ty * TM;
  const int tN = tx * TN;
  if (CAUSAL && tN >= tM + TM) return;            // fully-masked tile

  const int zo = tz / zInner, zi = tz - zo * zInner;
  A += (long)zo * sAo + (long)zi * sAi;
  B += (long)zo * sBo + (long)zi * sBi;
  const long cBase = (long)zo * sCo + (long)zi * sCi;

  const int t = threadIdx.x;
  const int wave = t >> 6, lane = t & 63;
  const int wr = wave / WX, wc = wave % WX;
  const int q = lane >> 4, l16 = lane & 15;

  // ---- staging addresses (lane -> row lane/4, col-group (lane&3)^swz(row)) ----
  const bfu* aG[AI]; bfu* aL[AI];
  const bfu* bG[BI]; bfu* bL[BI];
#pragma unroll
  for (int i2 = 0; i2 < AI; i2++) {
    const int rb = (i2 * NW + wave) * 16;
    const int r  = rb + (lane >> 2);
    const int g  = (lane & 3) ^ ((r >> 1) & 3);
    aG[i2] = A + (long)(tM + r) * lda + g * 8;
    aL[i2] = &As[rb * 32];
  }
#pragma unroll
  for (int i2 = 0; i2 < BI; i2++) {
    const int rb = (i2 * NW + wave) * 16;
    const int r  = rb + (lane >> 2);
    const int g  = (lane & 3) ^ ((r >> 1) & 3);
    bG[i2] = B + (long)(tN + r) * ldb + g * 8;
    bL[i2] = &Bs[rb * 32];
  }

  // ---- fragment LDS offsets (swizzled; k-invariant, per panel) ----
  int aOff[FI], bOff[FJ];
#pragma unroll
  for (int i = 0; i < FI; i++) {
    const int r = wr * FI * 16 + i * 16 + l16;
    aOff[i] = r * 32 + ((q ^ ((r >> 1) & 3)) * 8);
  }
#pragma unroll
  for (int j = 0; j < FJ; j++) {
    const int r = wc * FJ * 16 + j * 16 + l16;
    bOff[j] = r * 32 + ((q ^ ((r >> 1) & 3)) * 8);
  }

  const int Kend = TRIK ? ((tM + TM < K) ? tM + TM : K) : K;
  const int nt   = Kend >> 5;                     // BK=32 stages (>= 4)

  // stage panel pan with K-offset k (LP async16 per wave)
  auto stage = [&](int pan, int k) {
#pragma unroll
    for (int i2 = 0; i2 < AI; i2++) async16(aG[i2] + k, aL[i2] + pan * APAN);
#pragma unroll
    for (int i2 = 0; i2 < BI; i2++) async16(bG[i2] + k, bL[i2] + pan * BPAN);
  };

  f32x4 acc[FI][FJ] = {};

  // compute one staged panel from LDS
  auto compute = [&](int pan) {
    s16x8 af[FI], bfr[FJ];
#pragma unroll
    for (int i = 0; i < FI; i++) af[i]  = *(const s16x8*)&As[pan * APAN + aOff[i]];
#pragma unroll
    for (int j = 0; j < FJ; j++) bfr[j] = *(const s16x8*)&Bs[pan * BPAN + bOff[j]];
    __builtin_amdgcn_s_setprio(1);
#pragma unroll
    for (int i = 0; i < FI; i++)
#pragma unroll
      for (int j = 0; j < FJ; j++)
        acc[i][j] = __builtin_amdgcn_mfma_f32_16x16x32_bf16(af[i], bfr[j], acc[i][j], 0, 0, 0);
    __builtin_amdgcn_s_setprio(0);
  };

  // prologue: depth-2 prefetch (nt >= 4 at all call sites)
  stage(0, 0);
  stage(1, 32);

  if constexpr (NPAN == 3) {
    int pc = 0, ps = 2;                           // current / stage-ahead panel
    for (int tt = 0; tt < nt; ++tt) {
      if (tt + 2 < nt) { stage(ps, (tt + 2) * 32); waitvm<2 * LP>(); }
      else if (tt + 1 < nt) waitvm<LP>();
      else waitvm<0>();
      __builtin_amdgcn_s_barrier();               // panel pc ready (all waves)
      __builtin_amdgcn_sched_barrier(0);          // pin ds_reads below barrier
      compute(pc);
      __builtin_amdgcn_s_barrier();               // reads of pc done -> reusable
      pc = (pc == 2) ? 0 : pc + 1;
      ps = (ps == 2) ? 0 : ps + 1;
    }
  } else {
    for (int tt = 0; tt < nt; ++tt) {
      const int pc = tt & 3;
      if (tt + 2 < nt) { stage((tt + 2) & 3, (tt + 2) * 32); waitvm<2 * LP>(); }
      else if (tt + 1 < nt) waitvm<LP>();
      else waitvm<0>();
      __builtin_amdgcn_s_barrier();               // panel pc staged (all waves)
      __builtin_amdgcn_sched_barrier(0);          // pin ds_reads below barrier
      compute(pc);
    }
  }

  // Epilogue. C/D layout (m89/m91): col = lane&15, row = (lane>>4)*4 + reg.
  float* Cf = (float*)Cv;
  bfu*   Cb = (bfu*)Cv;
#pragma unroll
  for (int i = 0; i < FI; i++) {
    const int row0 = tM + wr * FI * 16 + i * 16 + q * 4;
#pragma unroll
    for (int j = 0; j < FJ; j++) {
      const int col = tN + wc * FJ * 16 + j * 16 + l16;
      float cbv = 0.0f;
      if (BIAS == 1) cbv = bias[col];
#pragma unroll
      for (int r = 0; r < 4; r++) {
        float v = acc[i][j][r];
        if (CAUSAL) { v *= scale; if (col > row0 + r) v = -1e30f; }
        if (BIAS == 1) v += cbv;
        if (BIAS == 2) v += bias[row0 + r];
        if (RELU) v = fmaxf(v, 0.0f);
        long idxc = cBase + (long)(row0 + r) * ldc + col;
        if (OUT_BF16) Cb[idxc] = f2b(v); else Cf[idxc] = v;
      }
    }
  }
}

// ---------------------------------------------------------------------------
// fp32 [R,C] -> bf16 [C,R] transpose+convert (used for W_out)
// pad 66: transposed-read bank stride 33 -> conflict-free
// ---------------------------------------------------------------------------
__global__ void transpose_cvt(const float* __restrict__ src, bfu* __restrict__ dst,
                              int R, int C)
{
  __shared__ bfu tile[64 * 66];
  const int t = threadIdx.x;
  const int tc = blockIdx.x * 64, tr = blockIdx.y * 64;
#pragma unroll
  for (int i = 0; i < 16; i++) {
    int idx = t + i * 256; int r = idx >> 6, c = idx & 63;
    tile[r * 66 + c] = f2b(src[(long)(tr + r) * C + tc + c]);
  }
  __syncthreads();
#pragma unroll
  for (int i = 0; i < 16; i++) {
    int idx = t + i * 256; int r = idx >> 6, c = idx & 63;
    dst[(long)(tc + r) * R + tr + c] = tile[c * 66 + r];
  }
}

// ---------------------------------------------------------------------------
// Fused per-layer weight prep (transposes + q|k bias pack). 2592 blocks.
// ---------------------------------------------------------------------------
__global__ void prep_layer(const float* __restrict__ Wq, const float* __restrict__ Wk,
                           const float* __restrict__ Wv, const float* __restrict__ Wo,
                           const float* __restrict__ W1, const float* __restrict__ W2,
                           const float* __restrict__ bq, const float* __restrict__ bk,
                           bfu* __restrict__ qkvwT, bfu* __restrict__ woT,
                           bfu* __restrict__ w1T, bfu* __restrict__ w2T,
                           float* __restrict__ qkb)
{
  const int bid = blockIdx.x;
  const int t = threadIdx.x;

  if (bid >= 2560) {                        // bias pack: 8192 elems, 32 blocks
    int j = (bid - 2560) * 256 + t;
    qkb[j] = (j < 4096) ? bq[j] : bk[j - 4096];
    return;
  }

  const float* src; bfu* dst; int R, C, ctiles, local;
  if (bid < 512)       { src = Wq; dst = qkvwT;              R = 512;  C = 4096; ctiles = 64; local = bid; }
  else if (bid < 1024) { src = Wk; dst = qkvwT + 4096L*512;  R = 512;  C = 4096; ctiles = 64; local = bid - 512; }
  else if (bid < 1536) { src = Wv; dst = qkvwT + 8192L*512;  R = 512;  C = 4096; ctiles = 64; local = bid - 1024; }
  else if (bid < 2048) { src = Wo; dst = woT;                R = 4096; C = 512;  ctiles = 8;  local = bid - 1536; }
  else if (bid < 2304) { src = W1; dst = w1T;                R = 512;  C = 2048; ctiles = 32; local = bid - 2048; }
  else                 { src = W2; dst = w2T;                R = 2048; C = 512;  ctiles = 8;  local = bid - 2304; }
  const int tc = (local % ctiles) * 64;
  const int tr = (local / ctiles) * 64;

  __shared__ bfu tile[64 * 66];
#pragma unroll
  for (int i = 0; i < 16; i++) {
    int idx = t + i * 256; int r = idx >> 6, c = idx & 63;
    tile[r * 66 + c] = f2b(src[(long)(tr + r) * C + tc + c]);
  }
  __syncthreads();
#pragma unroll
  for (int i = 0; i < 16; i++) {
    int idx = t + i * 256; int r = idx >> 6, c = idx & 63;
    dst[(long)(tc + r) * R + tr + c] = tile[c * 66 + r];
  }
}

// block (256 threads) stats over 512 values (2/thread pre-summed by caller)
__device__ __forceinline__ void blk_stats(float s, float ss, float* red,
                                          float& mean, float& var)
{
#pragma unroll
  for (int off = 32; off; off >>= 1) { s += __shfl_down(s, off); ss += __shfl_down(ss, off); }
  int w = threadIdx.x >> 6;
  if ((threadIdx.x & 63) == 0) { red[w] = s; red[4 + w] = ss; }
  __syncthreads();
  s  = red[0] + red[1] + red[2] + red[3];
  ss = red[4] + red[5] + red[6] + red[7];
  mean = s * (1.0f / 512.0f);
  var  = ss * (1.0f / 512.0f) - mean * mean;
}

__global__ void embed_ln(const int* __restrict__ ids, const float* __restrict__ tok,
                         const float* __restrict__ pos, const float* __restrict__ g,
                         const float* __restrict__ bta, float* __restrict__ h,
                         bfu* __restrict__ hb)
{
  __shared__ float red[8];
  const int row = blockIdx.x;          // b*S + s
  const int s = row & 1023;
  const int t = threadIdx.x;
  const long base = (long)row * 512;
  const int id = ids[row];
  float x0 = tok[(long)id * 512 + t]       + pos[(long)s * 512 + t];
  float x1 = tok[(long)id * 512 + t + 256] + pos[(long)s * 512 + t + 256];
  float mean, var;
  blk_stats(x0 + x1, x0 * x0 + x1 * x1, red, mean, var);
  float rstd = rsqrtf(var + 1e-5f);
  float y0 = (x0 - mean) * rstd * g[t]       + bta[t];
  float y1 = (x1 - mean) * rstd * g[t + 256] + bta[t + 256];
  h[base + t] = y0;        h[base + t + 256] = y1;
  hb[base + t] = f2b(y0);  hb[base + t + 256] = f2b(y1);
}

// x = sum_{s<n} p[i+s*ps] + bias[col] + h[i] -> LN -> h, hb
__global__ void add_ln_redN(const float* __restrict__ p, long ps, int n,
                            const float* __restrict__ bias,
                            float* __restrict__ h, bfu* __restrict__ hb,
                            const float* __restrict__ g, const float* __restrict__ bta)
{
  __shared__ float red[8];
  const long base = (long)blockIdx.x * 512;
  const int t = threadIdx.x;
  float x0 = bias[t]       + h[base + t];
  float x1 = bias[t + 256] + h[base + t + 256];
  for (int s = 0; s < n; s++) {
    x0 += p[base + (long)s * ps + t];
    x1 += p[base + (long)s * ps + t + 256];
  }
  float mean, var;
  blk_stats(x0 + x1, x0 * x0 + x1 * x1, red, mean, var);
  float rstd = rsqrtf(var + 1e-5f);
  float y0 = (x0 - mean) * rstd * g[t]       + bta[t];
  float y1 = (x1 - mean) * rstd * g[t + 256] + bta[t + 256];
  h[base + t] = y0;        h[base + t + 256] = y1;
  hb[base + t] = f2b(y0);  hb[base + t + 256] = f2b(y1);
}

// out[i] = sum_{s<n} p[i+s*ps] + bias[col]
__global__ void out_redN(const float* __restrict__ p, long ps, int n,
                         const float* __restrict__ bias, float* __restrict__ out)
{
  const long base = (long)blockIdx.x * 512;
  const int t = threadIdx.x;
  float x0 = bias[t], x1 = bias[t + 256];
  for (int s = 0; s < n; s++) {
    x0 += p[base + (long)s * ps + t];
    x1 += p[base + (long)s * ps + t + 256];
  }
  out[base + t] = x0;
  out[base + t + 256] = x1;
}

// Causal in-place softmax, row r = blockIdx.x & 1023 of a 1024-wide bf16 row.
// Vectorized: thread t owns 4 contiguous cols (u16x4 load/store).
// Reads cols <= r only (others masked); writes cols < roundup128(r+1).
__global__ void softmax_causal(bfu* __restrict__ P)
{
  __shared__ float red[8];
  const long base = (long)blockIdx.x * 1024;
  const int r = blockIdx.x & 1023;
  const int wlim = ((r >> 7) + 1) << 7;          // multiple of 128 (and of 4)
  const int t = threadIdx.x;
  const int c0 = t * 4;
  u16x4 pk = *(const u16x4*)&P[base + c0];
  float v[4];
  float mx = -3e30f;
#pragma unroll
  for (int i = 0; i < 4; i++) {
    const int col = c0 + i;
    v[i] = (col <= r) ? b2f(pk[i]) : -3e30f;
    mx = fmaxf(mx, v[i]);
  }
#pragma unroll
  for (int off = 32; off; off >>= 1) mx = fmaxf(mx, __shfl_xor(mx, off));
  int w = t >> 6;
  if ((t & 63) == 0) red[w] = mx;
  __syncthreads();
  mx = fmaxf(fmaxf(red[0], red[1]), fmaxf(red[2], red[3]));
  float e[4], sum = 0.0f;
#pragma unroll
  for (int i = 0; i < 4; i++) {
    const int col = c0 + i;
    e[i] = (col <= r) ? expf(v[i] - mx) : 0.0f;
    sum += e[i];
  }
#pragma unroll
  for (int off = 32; off; off >>= 1) sum += __shfl_xor(sum, off);
  __syncthreads();
  if ((t & 63) == 0) red[4 + w] = sum;
  __syncthreads();
  sum = red[4] + red[5] + red[6] + red[7];
  float inv = 1.0f / sum;
  if (c0 < wlim) {
    u16x4 o;
#pragma unroll
    for (int i = 0; i < 4; i++) o[i] = f2b(e[i] * inv);
    *(u16x4*)&P[base + c0] = o;
  }
}

// ---------------------------------------------------------------------------
extern "C" void kernel_launch(void* const* d_in, const int* in_sizes, int n_in,
                              void* d_out, int out_size, void* d_ws, size_t ws_size,
                              hipStream_t stream)
{
  const int*   x     = (const int*)  d_in[0];
  const float* tok   = (const float*)d_in[1];
  const float* pos   = (const float*)d_in[2];
  const float* lnig  = (const float*)d_in[3];
  const float* lnib  = (const float*)d_in[4];
  const float* Wq    = (const float*)d_in[5];
  const float* bq    = (const float*)d_in[6];
  const float* Wk    = (const float*)d_in[7];
  const float* bk    = (const float*)d_in[8];
  const float* Wv    = (const float*)d_in[9];
  const float* bv    = (const float*)d_in[10];
  const float* Wo    = (const float*)d_in[11];
  const float* bo    = (const float*)d_in[12];
  const float* ln1g  = (const float*)d_in[13];
  const float* ln1b  = (const float*)d_in[14];
  const float* W1    = (const float*)d_in[15];
  const float* b1    = (const float*)d_in[16];
  const float* W2    = (const float*)d_in[17];
  const float* b2    = (const float*)d_in[18];
  const float* ln2g  = (const float*)d_in[19];
  const float* ln2b  = (const float*)d_in[20];
  const float* Wout  = (const float*)d_in[21];
  const float* bout  = (const float*)d_in[22];

  // ---- workspace tiering (deterministic in ws_size) ----
  const size_t MB = 1024 * 1024;
  int gb; bool s4;                           // batches per attention group; split-K=4 path
  if      (ws_size >= 236 * MB) { gb = 4; s4 = true;  }
  else if (ws_size >= 169 * MB) { gb = 2; s4 = true;  }
  else if (ws_size >= 152 * MB) { gb = 1; s4 = true;  }
  else                          { gb = 1; s4 = false; }   // == round-4 layout (~110 MB)

  const size_t qkBytes = (size_t)gb * 1024 * 8192 * 2;
  const size_t scB0    = (size_t)gb * 8 * 1024 * 1024 * 2;
  const size_t scBytes = s4 ? (scB0 > 33554432 ? scB0 : 33554432) : 16777216;
  const size_t vtB0    = (size_t)gb * 8 * 512 * 1024 * 2;
  const size_t vtBytes = s4 ? (vtB0 > 33554432 ? vtB0 : 33554432) : 8388608;

  char* wsp = (char*)d_ws;
  auto alloc = [&](size_t bytes) { char* p = wsp; wsp += (bytes + 255) & ~(size_t)255; return p; };

  bfu*   qkvwT = (bfu*)  alloc(12288L * 512 * 2);
  bfu*   woT   = (bfu*)  alloc(512L * 4096 * 2);
  bfu*   w1T   = (bfu*)  alloc(2048L * 512 * 2);
  bfu*   w2T   = (bfu*)  alloc(512L * 2048 * 2);
  bfu*   woutT = (bfu*)  alloc(512L * 512 * 2);
  float* qkb   = (float*)alloc(8192L * 4);
  float* h     = (float*)alloc(4096L * 512 * 4);        // fp32 residual stream
  bfu*   hb    = (bfu*)  alloc(4096L * 512 * 2);        // bf16 copy (GEMM A operand)
  bfu*   attn  = (bfu*)  alloc(4096L * 4096 * 2);       // attention out, all tokens
  bfu*   qkS   = (bfu*)  alloc(qkBytes);                // q|k group; (!s4) FFN2/final partials
  bfu*   scS   = (bfu*)  alloc(scBytes);                // scores; Wo partials; FFN hidden
  bfu*   vTS   = (bfu*)  alloc(vtBytes);                // v^T group; (s4) FFN2/final partials

  float* pWo = (float*)scS;
  float* pF  = s4 ? (float*)vTS : (float*)qkS;
  const int nspl = s4 ? 4 : 2;

  embed_ln<<<4096, 256, 0, stream>>>(x, tok, pos, lnig, lnib, h, hb);
  transpose_cvt<<<dim3(8, 8), 256, 0, stream>>>(Wout, woutT, 512, 512);

  const float invsq = 0.044194173824159216f;  // 1/sqrt(512)
  const long  PSTR  = 4096L * 512;            // split-K partial stride (floats)

  for (int l = 0; l < 6; l++) {
    prep_layer<<<2592, 256, 0, stream>>>(
        Wq + (long)l*512*4096, Wk + (long)l*512*4096, Wv + (long)l*512*4096,
        Wo + (long)l*4096*512, W1 + (long)l*512*2048, W2 + (long)l*2048*512,
        bq + (long)l*4096, bk + (long)l*4096,
        qkvwT, woT, w1T, w2T, qkb);

    for (int g0 = 0; g0 < 4; g0 += gb) {
      const bfu* hbG = hb + (long)g0 * 1024 * 512;

      // q|k: [gb*1024,512] x [8192,512]^T -> qkS (+col bias). 3-panel core.
      gemm_bt<128,128,2,2,4,4,true,false,false,1,false,3>
          <<<dim3(64, gb*8, 1), 256, 0, stream>>>(
          hbG, 512, 0, 0, qkvwT, 512, 0, 0, qkS, 8192, 0, 0,
          qkb, 512, 1, 1.0f, 8);

      // vT[b][h][d][s] = Wv^T @ h_b^T (+row bias): z = batch. 4-panel core.
      gemm_bt<128,128,2,2,4,4,true,false,false,2,false,4>
          <<<dim3(8, 32, gb), 256, 0, stream>>>(
          qkvwT + 8192L*512, 512, 0, 0,
          hbG, 512, 0, 1024L*512,
          vTS, 1024, 0, 4096L*1024,
          bv + (long)l*4096, 512, gb, 1.0f, 8);

      // scores = (q k^T)/sqrt(dh), causal: z = b*8+h. 3-panel (2048 blocks).
      gemm_bt<128,128,2,2,4,4,true,false,true,0,false,3>
          <<<dim3(8, 8, gb*8), 256, 0, stream>>>(
          qkS,        8192, 1024L*8192, 512,
          qkS + 4096, 8192, 1024L*8192, 512,
          scS, 1024, 8L*1024*1024, 1024L*1024,
          nullptr, 512, 8, invsq, 8);

      softmax_causal<<<gb*8192, 256, 0, stream>>>(scS);

      // attn = P @ v, triangular K: z = b*8+h. 3-panel (2048 blocks, 36KB).
      gemm_bt<128,64,2,2,4,2,true,false,false,0,true,3>
          <<<dim3(8, 8, gb*8), 256, 0, stream>>>(
          scS, 1024, 8L*1024*1024, 1024L*1024,
          vTS, 1024, 8L*512*1024,  512L*1024,
          attn + (long)g0*1024*4096, 4096, 1024L*4096, 512,
          nullptr, 1024, 8, 1.0f, 8);
    }

    // Wo projection -> fp32 partials
    if (s4) {
      gemm_bt<128,128,2,2,4,4,false,false,false,0,false,4>
          <<<dim3(4, 32, 4), 256, 0, stream>>>(
          attn, 4096, 0, 1024, woT, 4096, 0, 1024,
          pWo, 512, 0, PSTR, nullptr, 1024, 4, 1.0f, 4);
    } else {
      gemm_bt<128,64,2,2,4,2,false,false,false,0,false,4>
          <<<dim3(8, 32, 2), 256, 0, stream>>>(
          attn, 4096, 0, 2048, woT, 4096, 0, 2048,
          pWo, 512, 0, PSTR, nullptr, 2048, 1, 1.0f, 8);
    }
    add_ln_redN<<<4096, 256, 0, stream>>>(pWo, PSTR, nspl, bo + (long)l*512,
                                          h, hb, ln1g + (long)l*512, ln1b + (long)l*512);

    // FFN1 (+ReLU) -> bf16 hidden in scS [4096,2048]
    gemm_bt<128,128,2,2,4,4,true,true,false,1,false,4>
        <<<dim3(16, 32, 1), 256, 0, stream>>>(
        hb, 512, 0, 0, w1T, 512, 0, 0, scS, 2048, 0, 0,
        b1 + (long)l*2048, 512, 1, 1.0f, 16);

    // FFN2 -> fp32 partials
    if (s4) {
      gemm_bt<128,128,2,2,4,4,false,false,false,0,false,4>
          <<<dim3(4, 32, 4), 256, 0, stream>>>(
          scS, 2048, 0, 512, w2T, 2048, 0, 512,
          pF, 512, 0, PSTR, nullptr, 512, 4, 1.0f, 4);
    } else {
      gemm_bt<128,64,2,2,4,2,false,false,false,0,false,4>
          <<<dim3(8, 32, 2), 256, 0, stream>>>(
          scS, 2048, 0, 1024, w2T, 2048, 0, 1024,
          pF, 512, 0, PSTR, nullptr, 1024, 1, 1.0f, 8);
    }
    add_ln_redN<<<4096, 256, 0, stream>>>(pF, PSTR, nspl, b2 + (long)l*512,
                                          h, hb, ln2g + (long)l*512, ln2b + (long)l*512);
  }

  // final projection (K=128 per split: multiple of 64 ✓)
  if (s4) {
    gemm_bt<128,128,2,2,4,4,false,false,false,0,false,4>
        <<<dim3(4, 32, 4), 256, 0, stream>>>(
        hb, 512, 0, 128, woutT, 512, 0, 128,
        pF, 512, 0, PSTR, nullptr, 128, 4, 1.0f, 4);
  } else {
    gemm_bt<128,64,2,2,4,2,false,false,false,0,false,4>
        <<<dim3(8, 32, 2), 256, 0, stream>>>(
        hb, 512, 0, 256, woutT, 512, 0, 256,
        pF, 512, 0, PSTR, nullptr, 256, 1, 1.0f, 8);
  }
  out_redN<<<4096, 256, 0, stream>>>(pF, PSTR, nspl, bout, (float*)d_out);
}